// Round 1
// baseline (11535.123 us; speedup 1.0000x reference)
//
#include <hip/hip_runtime.h>
#include <hip/hip_bf16.h>

#define N_NODES 100000
#define N_EDGES 1600000
#define IN_DIM 128
#define HID 256
#define NUM_GRAPHS 2048

// ---------------- degree / dinv ----------------
__global__ void count_deg_kernel(const int* __restrict__ ei, int* __restrict__ deg) {
    int e = blockIdx.x * blockDim.x + threadIdx.x;
    if (e < N_EDGES) {
        atomicAdd(&deg[ei[N_EDGES + e]], 1);
    }
}

__global__ void dinv_kernel(const int* __restrict__ deg, float* __restrict__ dinv) {
    int n = blockIdx.x * blockDim.x + threadIdx.x;
    if (n < N_NODES) {
        // self-loop adds 1; deg >= 1 always
        dinv[n] = rsqrtf((float)(deg[n] + 1));
    }
}

// ---------------- SGEMM: C[M,256] = A[M,K] @ B[K,256] ----------------
// BM=64, BN=64, BK=16, 256 threads, 4x4 micro-tile per thread.
template <int K>
__launch_bounds__(256)
__global__ void sgemm_kernel(const float* __restrict__ A, const float* __restrict__ B,
                             float* __restrict__ C, int M) {
    const int N = 256;
    __shared__ float As[16][64];  // [k][m] (transposed for coalesced LDS reads)
    __shared__ float Bs[16][64];  // [k][n]

    int tid = threadIdx.x;
    int tx = tid & 15;        // col group 0..15
    int ty = tid >> 4;        // row group 0..15
    int block_m = blockIdx.x * 64;
    int block_n = blockIdx.y * 64;

    // A-load mapping: each thread loads a float4 along K
    int arow = tid >> 2;            // 0..63
    int acol = (tid & 3) * 4;       // 0,4,8,12
    // B-load mapping
    int brow = tid >> 4;            // 0..15
    int bcol = (tid & 15) * 4;      // 0..60

    float acc[4][4];
#pragma unroll
    for (int i = 0; i < 4; i++)
#pragma unroll
        for (int j = 0; j < 4; j++) acc[i][j] = 0.0f;

    for (int k0 = 0; k0 < K; k0 += 16) {
        // load A tile (guard M)
        float4 av = make_float4(0.f, 0.f, 0.f, 0.f);
        int gm = block_m + arow;
        if (gm < M) av = *(const float4*)(A + (size_t)gm * K + k0 + acol);
        As[acol + 0][arow] = av.x;
        As[acol + 1][arow] = av.y;
        As[acol + 2][arow] = av.z;
        As[acol + 3][arow] = av.w;
        // load B tile (N=256 always in-bounds)
        float4 bv = *(const float4*)(B + (size_t)(k0 + brow) * N + block_n + bcol);
        *(float4*)&Bs[brow][bcol] = bv;
        __syncthreads();

#pragma unroll
        for (int kk = 0; kk < 16; kk++) {
            float a[4], b[4];
#pragma unroll
            for (int i = 0; i < 4; i++) a[i] = As[kk][ty * 4 + i];
#pragma unroll
            for (int j = 0; j < 4; j++) b[j] = Bs[kk][tx * 4 + j];
#pragma unroll
            for (int i = 0; i < 4; i++)
#pragma unroll
                for (int j = 0; j < 4; j++) acc[i][j] = fmaf(a[i], b[j], acc[i][j]);
        }
        __syncthreads();
    }

#pragma unroll
    for (int i = 0; i < 4; i++) {
        int m = block_m + ty * 4 + i;
        if (m < M) {
            float4 v = make_float4(acc[i][0], acc[i][1], acc[i][2], acc[i][3]);
            *(float4*)(C + (size_t)m * N + block_n + tx * 4) = v;
        }
    }
}

// ---------------- edge scatter: agg[dst] += dinv[src]*dinv[dst]*H[src] ----------------
// one 64-lane wave per edge; lane handles 4 consecutive features
__global__ void scatter_kernel(const float* __restrict__ H, const int* __restrict__ ei,
                               const float* __restrict__ dinv, float* __restrict__ agg) {
    int gt = blockIdx.x * blockDim.x + threadIdx.x;
    int e = gt >> 6;
    int lane = threadIdx.x & 63;
    if (e >= N_EDGES) return;
    int src = ei[e];
    int dst = ei[N_EDGES + e];
    float w = dinv[src] * dinv[dst];
    float4 h4 = *(const float4*)(H + (size_t)src * HID + lane * 4);
    float* a = agg + (size_t)dst * HID + lane * 4;
    unsafeAtomicAdd(a + 0, w * h4.x);
    unsafeAtomicAdd(a + 1, w * h4.y);
    unsafeAtomicAdd(a + 2, w * h4.z);
    unsafeAtomicAdd(a + 3, w * h4.w);
}

// ---------------- finish: agg = relu(agg + dinv^2 * H + b) ----------------
__global__ void finish_kernel(float* __restrict__ agg, const float* __restrict__ H,
                              const float* __restrict__ dinv, const float* __restrict__ b) {
    size_t i = ((size_t)blockIdx.x * blockDim.x + threadIdx.x) * 4;
    int v = (int)(i >> 8);
    int f = (int)(i & 255);
    float s = dinv[v];
    float w = s * s;
    float4 a = *(float4*)(agg + i);
    float4 h = *(const float4*)(H + i);
    float4 bb = *(const float4*)(b + f);
    a.x = fmaxf(fmaf(w, h.x, a.x) + bb.x, 0.f);
    a.y = fmaxf(fmaf(w, h.y, a.y) + bb.y, 0.f);
    a.z = fmaxf(fmaf(w, h.z, a.z) + bb.z, 0.f);
    a.w = fmaxf(fmaf(w, h.w, a.w) + bb.w, 0.f);
    *(float4*)(agg + i) = a;
}

// ---------------- pooling: pooled[batch[n]] += h[n]; cnt[batch[n]] += 1 ----------------
__global__ void pool_kernel(const float* __restrict__ h, const int* __restrict__ batch,
                            float* __restrict__ pooled, float* __restrict__ cnt) {
    int gt = blockIdx.x * blockDim.x + threadIdx.x;
    int n = gt >> 6;
    int lane = threadIdx.x & 63;
    if (n >= N_NODES) return;
    int g = batch[n];
    float4 v = *(const float4*)(h + (size_t)n * HID + lane * 4);
    float* p = pooled + (size_t)g * HID + lane * 4;
    unsafeAtomicAdd(p + 0, v.x);
    unsafeAtomicAdd(p + 1, v.y);
    unsafeAtomicAdd(p + 2, v.z);
    unsafeAtomicAdd(p + 3, v.w);
    if (lane == 0) unsafeAtomicAdd(cnt + g, 1.0f);
}

// ---------------- MLP head: out[g] = relu(mean @ Wf1 + bf1) @ Wf2 + bf2 ----------------
__launch_bounds__(128)
__global__ void mlp_kernel(const float* __restrict__ pooled, const float* __restrict__ cnt,
                           const float* __restrict__ Wf1, const float* __restrict__ bf1,
                           const float* __restrict__ Wf2, const float* __restrict__ bf2,
                           float* __restrict__ out) {
    int g = blockIdx.x;
    int t = threadIdx.x;  // 0..127
    __shared__ float p[256];
    __shared__ float partial[2];
    float inv = 1.0f / fmaxf(cnt[g], 1.0f);
    p[t] = pooled[(size_t)g * 256 + t] * inv;
    p[t + 128] = pooled[(size_t)g * 256 + 128 + t] * inv;
    __syncthreads();
    float acc = bf1[t];
#pragma unroll 8
    for (int k = 0; k < 256; k++) acc = fmaf(p[k], Wf1[k * 128 + t], acc);
    float hv = fmaxf(acc, 0.f) * Wf2[t];
#pragma unroll
    for (int off = 32; off > 0; off >>= 1) hv += __shfl_down(hv, off, 64);
    if ((t & 63) == 0) partial[t >> 6] = hv;
    __syncthreads();
    if (t == 0) out[g] = partial[0] + partial[1] + bf2[0];
}

extern "C" void kernel_launch(void* const* d_in, const int* in_sizes, int n_in,
                              void* d_out, int out_size, void* d_ws, size_t ws_size,
                              hipStream_t stream) {
    const float* x   = (const float*)d_in[0];
    const int*   ei  = (const int*)d_in[1];
    const int*   bat = (const int*)d_in[2];
    const float* W1  = (const float*)d_in[3];
    const float* b1  = (const float*)d_in[4];
    const float* W2  = (const float*)d_in[5];
    const float* b2  = (const float*)d_in[6];
    const float* Wf1 = (const float*)d_in[7];
    const float* bf1 = (const float*)d_in[8];
    const float* Wf2 = (const float*)d_in[9];
    const float* bf2 = (const float*)d_in[10];
    float* out = (float*)d_out;

    char* ws = (char*)d_ws;
    // layout (bytes):
    //   0x0000000: deg   (100000 int, 400000 B)
    //   0x0080000: dinv  (100000 f32)
    //   0x0100000: cnt   (2048 f32)
    //   0x0110000: pooled(2048*256 f32 = 2 MB)
    //   0x0310000: bufA  (100000*256 f32 = 102,400,000 B = 0x61A8000)
    //   0x64B8000: bufB  (same)
    int*   deg    = (int*)(ws);
    float* dinv   = (float*)(ws + 0x0080000);
    float* cnt    = (float*)(ws + 0x0100000);
    float* pooled = (float*)(ws + 0x0110000);
    float* bufA   = (float*)(ws + 0x0310000);
    float* bufB   = (float*)(ws + 0x64B8000);
    const size_t BIG = (size_t)N_NODES * HID * sizeof(float);  // 102,400,000

    // zero accumulators (ws is poisoned 0xAA before every call)
    hipMemsetAsync(deg, 0, (size_t)N_NODES * sizeof(int), stream);
    hipMemsetAsync(ws + 0x0100000, 0, 0x210000, stream);  // cnt + pooled

    count_deg_kernel<<<(N_EDGES + 255) / 256, 256, 0, stream>>>(ei, deg);
    dinv_kernel<<<(N_NODES + 255) / 256, 256, 0, stream>>>(deg, dinv);

    // layer 1: H = x @ W1
    {
        dim3 grid((N_NODES + 63) / 64, 4);
        sgemm_kernel<IN_DIM><<<grid, 256, 0, stream>>>(x, W1, bufA, N_NODES);
    }
    hipMemsetAsync(bufB, 0, BIG, stream);
    scatter_kernel<<<N_EDGES / 4, 256, 0, stream>>>(bufA, ei, dinv, bufB);
    finish_kernel<<<(N_NODES * HID / 4) / 256, 256, 0, stream>>>(bufB, bufA, dinv, b1);

    // layer 2: H2 = h1 @ W2
    {
        dim3 grid((N_NODES + 63) / 64, 4);
        sgemm_kernel<HID><<<grid, 256, 0, stream>>>(bufB, W2, bufA, N_NODES);
    }
    hipMemsetAsync(bufB, 0, BIG, stream);
    scatter_kernel<<<N_EDGES / 4, 256, 0, stream>>>(bufA, ei, dinv, bufB);
    finish_kernel<<<(N_NODES * HID / 4) / 256, 256, 0, stream>>>(bufB, bufA, dinv, b2);

    // pooling
    pool_kernel<<<(N_NODES * 64) / 256, 256, 0, stream>>>(bufB, bat, pooled, cnt);

    // MLP head
    mlp_kernel<<<NUM_GRAPHS, 128, 0, stream>>>(pooled, cnt, Wf1, bf1, Wf2, bf2, out);
}

// Round 2
// 1214.201 us; speedup vs baseline: 9.5002x; 9.5002x over previous
//
#include <hip/hip_runtime.h>
#include <hip/hip_bf16.h>

#define N_NODES 100000
#define N_EDGES 1600000
#define IN_DIM 128
#define HID 256
#define NUM_GRAPHS 2048

// ---------------- degree histogram over dst ----------------
__global__ void count_deg_kernel(const int* __restrict__ ei, int* __restrict__ deg) {
    int e = blockIdx.x * blockDim.x + threadIdx.x;
    if (e < N_EDGES) {
        atomicAdd(&deg[ei[N_EDGES + e]], 1);
    }
}

__global__ void dinv_kernel(const int* __restrict__ deg, float* __restrict__ dinv) {
    int n = blockIdx.x * blockDim.x + threadIdx.x;
    if (n < N_NODES) {
        // self-loop adds 1; deg >= 1 always
        dinv[n] = rsqrtf((float)(deg[n] + 1));
    }
}

// ---------------- exclusive prefix sum over deg -> rowptr[N+1] ----------------
// single block of 1024; each thread owns a contiguous chunk of ~98 elements
__global__ __launch_bounds__(1024) void scan_kernel(const int* __restrict__ deg,
                                                    int* __restrict__ rowptr) {
    const int C = (N_NODES + 1023) / 1024;  // 98
    int t = threadIdx.x;
    int start = t * C;
    int end = min(start + C, N_NODES);
    int sum = 0;
    for (int i = start; i < end; i++) sum += deg[i];
    __shared__ int sdata[1024];
    sdata[t] = sum;
    __syncthreads();
    // Hillis-Steele inclusive scan
    for (int off = 1; off < 1024; off <<= 1) {
        int x = (t >= off) ? sdata[t - off] : 0;
        __syncthreads();
        sdata[t] += x;
        __syncthreads();
    }
    int run = (t > 0) ? sdata[t - 1] : 0;
    for (int i = start; i < end; i++) {
        rowptr[i] = run;
        run += deg[i];
    }
    if (t == 1023) rowptr[N_NODES] = run;  // == N_EDGES
}

// ---------------- bucket fill: CSR src list sorted by dst ----------------
__global__ void fill_kernel(const int* __restrict__ ei, const int* __restrict__ rowptr,
                            int* __restrict__ fill, int* __restrict__ esrc) {
    int e = blockIdx.x * blockDim.x + threadIdx.x;
    if (e < N_EDGES) {
        int dst = ei[N_EDGES + e];
        int pos = rowptr[dst] + atomicAdd(&fill[dst], 1);
        esrc[pos] = ei[e];
    }
}

// ---------------- SGEMM: C[M,256] = A[M,K] @ B[K,256] ----------------
// BM=64, BN=64, BK=16, 256 threads, 4x4 micro-tile per thread.
template <int K>
__launch_bounds__(256)
__global__ void sgemm_kernel(const float* __restrict__ A, const float* __restrict__ B,
                             float* __restrict__ C, int M) {
    const int N = 256;
    __shared__ float As[16][64];  // [k][m]
    __shared__ float Bs[16][64];  // [k][n]

    int tid = threadIdx.x;
    int tx = tid & 15;
    int ty = tid >> 4;
    int block_m = blockIdx.x * 64;
    int block_n = blockIdx.y * 64;

    int arow = tid >> 2;
    int acol = (tid & 3) * 4;
    int brow = tid >> 4;
    int bcol = (tid & 15) * 4;

    float acc[4][4];
#pragma unroll
    for (int i = 0; i < 4; i++)
#pragma unroll
        for (int j = 0; j < 4; j++) acc[i][j] = 0.0f;

    for (int k0 = 0; k0 < K; k0 += 16) {
        float4 av = make_float4(0.f, 0.f, 0.f, 0.f);
        int gm = block_m + arow;
        if (gm < M) av = *(const float4*)(A + (size_t)gm * K + k0 + acol);
        As[acol + 0][arow] = av.x;
        As[acol + 1][arow] = av.y;
        As[acol + 2][arow] = av.z;
        As[acol + 3][arow] = av.w;
        float4 bv = *(const float4*)(B + (size_t)(k0 + brow) * N + block_n + bcol);
        *(float4*)&Bs[brow][bcol] = bv;
        __syncthreads();

#pragma unroll
        for (int kk = 0; kk < 16; kk++) {
            float a[4], b[4];
#pragma unroll
            for (int i = 0; i < 4; i++) a[i] = As[kk][ty * 4 + i];
#pragma unroll
            for (int j = 0; j < 4; j++) b[j] = Bs[kk][tx * 4 + j];
#pragma unroll
            for (int i = 0; i < 4; i++)
#pragma unroll
                for (int j = 0; j < 4; j++) acc[i][j] = fmaf(a[i], b[j], acc[i][j]);
        }
        __syncthreads();
    }

#pragma unroll
    for (int i = 0; i < 4; i++) {
        int m = block_m + ty * 4 + i;
        if (m < M) {
            float4 v = make_float4(acc[i][0], acc[i][1], acc[i][2], acc[i][3]);
            *(float4*)(C + (size_t)m * N + block_n + tx * 4) = v;
        }
    }
}

// ---------------- gather aggregation (fused self-loop + bias + relu) ----------------
// one 64-lane wave per dst node; lane handles 4 consecutive features
__global__ __launch_bounds__(256) void agg_kernel(const float* __restrict__ H,
                                                  const int* __restrict__ esrc,
                                                  const int* __restrict__ rowptr,
                                                  const float* __restrict__ dinv,
                                                  const float* __restrict__ b,
                                                  float* __restrict__ out) {
    int node = blockIdx.x * 4 + (threadIdx.x >> 6);
    int lane = threadIdx.x & 63;
    if (node >= N_NODES) return;
    float ddst = dinv[node];
    int s = rowptr[node], e = rowptr[node + 1];

    // self loop: weight dinv[node]^2
    float w0 = ddst * ddst;
    float4 h0 = *(const float4*)(H + (size_t)node * HID + lane * 4);
    float4 acc;
    acc.x = w0 * h0.x;
    acc.y = w0 * h0.y;
    acc.z = w0 * h0.z;
    acc.w = w0 * h0.w;

    for (int j = s; j < e; j++) {
        int src = esrc[j];
        float w = dinv[src] * ddst;
        float4 h = *(const float4*)(H + (size_t)src * HID + lane * 4);
        acc.x = fmaf(w, h.x, acc.x);
        acc.y = fmaf(w, h.y, acc.y);
        acc.z = fmaf(w, h.z, acc.z);
        acc.w = fmaf(w, h.w, acc.w);
    }

    float4 bb = *(const float4*)(b + lane * 4);
    acc.x = fmaxf(acc.x + bb.x, 0.f);
    acc.y = fmaxf(acc.y + bb.y, 0.f);
    acc.z = fmaxf(acc.z + bb.z, 0.f);
    acc.w = fmaxf(acc.w + bb.w, 0.f);
    *(float4*)(out + (size_t)node * HID + lane * 4) = acc;
}

// ---------------- fused mean-pool (batch is sorted) + MLP head ----------------
__global__ __launch_bounds__(256) void pool_mlp_kernel(const float* __restrict__ h,
                                                       const int* __restrict__ batch,
                                                       const float* __restrict__ Wf1,
                                                       const float* __restrict__ bf1,
                                                       const float* __restrict__ Wf2,
                                                       const float* __restrict__ bf2,
                                                       float* __restrict__ out) {
    int g = blockIdx.x;
    int t = threadIdx.x;  // 0..255
    __shared__ int bounds[2];
    if (t < 2) {
        int target = g + t;
        int lo = 0, hi = N_NODES;
        while (lo < hi) {
            int mid = (lo + hi) >> 1;
            if (batch[mid] < target) lo = mid + 1;
            else hi = mid;
        }
        bounds[t] = lo;
    }
    __syncthreads();
    int lo = bounds[0], hi = bounds[1];

    float acc = 0.f;
    for (int n = lo; n < hi; n++) acc += h[(size_t)n * HID + t];
    float inv = (hi > lo) ? 1.0f / (float)(hi - lo) : 0.f;  // cnt=0 -> pooled=0
    __shared__ float p[256];
    p[t] = acc * inv;
    __syncthreads();

    float hv = 0.f;
    if (t < 128) {
        float a = bf1[t];
#pragma unroll 8
        for (int k = 0; k < 256; k++) a = fmaf(p[k], Wf1[k * 128 + t], a);
        hv = fmaxf(a, 0.f) * Wf2[t];
    }
#pragma unroll
    for (int off = 32; off > 0; off >>= 1) hv += __shfl_down(hv, off, 64);
    __shared__ float partial[4];
    if ((t & 63) == 0) partial[t >> 6] = hv;
    __syncthreads();
    if (t == 0) out[g] = partial[0] + partial[1] + bf2[0];
}

extern "C" void kernel_launch(void* const* d_in, const int* in_sizes, int n_in,
                              void* d_out, int out_size, void* d_ws, size_t ws_size,
                              hipStream_t stream) {
    const float* x   = (const float*)d_in[0];
    const int*   ei  = (const int*)d_in[1];
    const int*   bat = (const int*)d_in[2];
    const float* W1  = (const float*)d_in[3];
    const float* b1  = (const float*)d_in[4];
    const float* W2  = (const float*)d_in[5];
    const float* b2  = (const float*)d_in[6];
    const float* Wf1 = (const float*)d_in[7];
    const float* bf1 = (const float*)d_in[8];
    const float* Wf2 = (const float*)d_in[9];
    const float* bf2 = (const float*)d_in[10];
    float* out = (float*)d_out;

    char* ws = (char*)d_ws;
    // layout (bytes):
    //   0x0000000: deg    (100000 int)
    //   0x0080000: dinv   (100000 f32)
    //   0x0100000: rowptr (100001 int)
    //   0x0180000: fill   (100000 int)
    //   0x0200000: esrc   (1.6M int = 6.4 MB)
    //   0x0900000: bufA   (100000*256 f32 = 102,400,000 B = 0x61A8000)
    //   0x6AA8000: bufB   (same)  -> total ~0xCC50000 = 214.3 MB
    int*   deg    = (int*)(ws);
    float* dinv   = (float*)(ws + 0x0080000);
    int*   rowptr = (int*)(ws + 0x0100000);
    int*   fill   = (int*)(ws + 0x0180000);
    int*   esrc   = (int*)(ws + 0x0200000);
    float* bufA   = (float*)(ws + 0x0900000);
    float* bufB   = (float*)(ws + 0x6AA8000);

    // zero the two histograms (ws is poisoned 0xAA before every call)
    hipMemsetAsync(deg, 0, (size_t)N_NODES * sizeof(int), stream);
    hipMemsetAsync(fill, 0, (size_t)N_NODES * sizeof(int), stream);

    // CSR build
    count_deg_kernel<<<(N_EDGES + 255) / 256, 256, 0, stream>>>(ei, deg);
    dinv_kernel<<<(N_NODES + 255) / 256, 256, 0, stream>>>(deg, dinv);
    scan_kernel<<<1, 1024, 0, stream>>>(deg, rowptr);
    fill_kernel<<<(N_EDGES + 255) / 256, 256, 0, stream>>>(ei, rowptr, fill, esrc);

    // layer 1: H = relu(agg(x @ W1) + b1)
    {
        dim3 grid((N_NODES + 63) / 64, 4);
        sgemm_kernel<IN_DIM><<<grid, 256, 0, stream>>>(x, W1, bufA, N_NODES);
    }
    agg_kernel<<<(N_NODES + 3) / 4, 256, 0, stream>>>(bufA, esrc, rowptr, dinv, b1, bufB);

    // layer 2
    {
        dim3 grid((N_NODES + 63) / 64, 4);
        sgemm_kernel<HID><<<grid, 256, 0, stream>>>(bufB, W2, bufA, N_NODES);
    }
    agg_kernel<<<(N_NODES + 3) / 4, 256, 0, stream>>>(bufA, esrc, rowptr, dinv, b2, bufB);

    // pooling + MLP head
    pool_mlp_kernel<<<NUM_GRAPHS, 256, 0, stream>>>(bufB, bat, Wf1, bf1, Wf2, bf2, out);
}

// Round 3
// 1082.434 us; speedup vs baseline: 10.6567x; 1.1217x over previous
//
#include <hip/hip_runtime.h>
#include <hip/hip_bf16.h>

#define N_NODES 100000
#define N_EDGES 1600000
#define IN_DIM 128
#define HID 256
#define NUM_GRAPHS 2048

// ---------------- degree histogram over dst ----------------
__global__ void count_deg_kernel(const int* __restrict__ ei, int* __restrict__ deg) {
    int e = blockIdx.x * blockDim.x + threadIdx.x;
    if (e < N_EDGES) {
        atomicAdd(&deg[ei[N_EDGES + e]], 1);
    }
}

__global__ void dinv_kernel(const int* __restrict__ deg, float* __restrict__ dinv) {
    int n = blockIdx.x * blockDim.x + threadIdx.x;
    if (n < N_NODES) {
        dinv[n] = rsqrtf((float)(deg[n] + 1));  // self-loop adds 1
    }
}

// ---------------- exclusive prefix sum over deg -> rowptr[N+1] ----------------
__global__ __launch_bounds__(1024) void scan_kernel(const int* __restrict__ deg,
                                                    int* __restrict__ rowptr) {
    const int C = (N_NODES + 1023) / 1024;  // 98
    int t = threadIdx.x;
    int start = t * C;
    int end = min(start + C, N_NODES);
    int sum = 0;
    for (int i = start; i < end; i++) sum += deg[i];
    __shared__ int sdata[1024];
    sdata[t] = sum;
    __syncthreads();
    for (int off = 1; off < 1024; off <<= 1) {
        int x = (t >= off) ? sdata[t - off] : 0;
        __syncthreads();
        sdata[t] += x;
        __syncthreads();
    }
    int run = (t > 0) ? sdata[t - 1] : 0;
    for (int i = start; i < end; i++) {
        rowptr[i] = run;
        run += deg[i];
    }
    if (t == 1023) rowptr[N_NODES] = run;
}

// ---------------- bucket fill: CSR src list sorted by dst ----------------
__global__ void fill_kernel(const int* __restrict__ ei, const int* __restrict__ rowptr,
                            int* __restrict__ fill, int* __restrict__ esrc) {
    int e = blockIdx.x * blockDim.x + threadIdx.x;
    if (e < N_EDGES) {
        int dst = ei[N_EDGES + e];
        int pos = rowptr[dst] + atomicAdd(&fill[dst], 1);
        esrc[pos] = ei[e];
    }
}

// ---------------- pure gather aggregation, 128-dim (float2/lane), 4x edge unroll ----
__global__ __launch_bounds__(256) void agg128_kernel(const float* __restrict__ H,
                                                     const int* __restrict__ esrc,
                                                     const int* __restrict__ rowptr,
                                                     const float* __restrict__ dinv,
                                                     float* __restrict__ out) {
    int node = blockIdx.x * 4 + (threadIdx.x >> 6);
    int lane = threadIdx.x & 63;
    if (node >= N_NODES) return;
    float ddst = dinv[node];
    int s = rowptr[node], e = rowptr[node + 1];

    float w0 = ddst * ddst;
    float2 h0 = *(const float2*)(H + (size_t)node * 128 + lane * 2);
    float2 acc = make_float2(w0 * h0.x, w0 * h0.y);

    int j = s;
    for (; j + 4 <= e; j += 4) {
        int s0 = esrc[j], s1 = esrc[j + 1], s2 = esrc[j + 2], s3 = esrc[j + 3];
        float a0 = dinv[s0] * ddst, a1 = dinv[s1] * ddst;
        float a2 = dinv[s2] * ddst, a3 = dinv[s3] * ddst;
        float2 x0 = *(const float2*)(H + (size_t)s0 * 128 + lane * 2);
        float2 x1 = *(const float2*)(H + (size_t)s1 * 128 + lane * 2);
        float2 x2 = *(const float2*)(H + (size_t)s2 * 128 + lane * 2);
        float2 x3 = *(const float2*)(H + (size_t)s3 * 128 + lane * 2);
        acc.x = fmaf(a0, x0.x, acc.x); acc.y = fmaf(a0, x0.y, acc.y);
        acc.x = fmaf(a1, x1.x, acc.x); acc.y = fmaf(a1, x1.y, acc.y);
        acc.x = fmaf(a2, x2.x, acc.x); acc.y = fmaf(a2, x2.y, acc.y);
        acc.x = fmaf(a3, x3.x, acc.x); acc.y = fmaf(a3, x3.y, acc.y);
    }
    for (; j < e; j++) {
        int src = esrc[j];
        float w = dinv[src] * ddst;
        float2 x = *(const float2*)(H + (size_t)src * 128 + lane * 2);
        acc.x = fmaf(w, x.x, acc.x);
        acc.y = fmaf(w, x.y, acc.y);
    }
    *(float2*)(out + (size_t)node * 128 + lane * 2) = acc;
}

// ---------------- pure gather aggregation, 256-dim (float4/lane), 4x edge unroll ----
__global__ __launch_bounds__(256) void agg256_kernel(const float* __restrict__ H,
                                                     const int* __restrict__ esrc,
                                                     const int* __restrict__ rowptr,
                                                     const float* __restrict__ dinv,
                                                     float* __restrict__ out) {
    int node = blockIdx.x * 4 + (threadIdx.x >> 6);
    int lane = threadIdx.x & 63;
    if (node >= N_NODES) return;
    float ddst = dinv[node];
    int s = rowptr[node], e = rowptr[node + 1];

    float w0 = ddst * ddst;
    float4 h0 = *(const float4*)(H + (size_t)node * 256 + lane * 4);
    float4 acc = make_float4(w0 * h0.x, w0 * h0.y, w0 * h0.z, w0 * h0.w);

    int j = s;
    for (; j + 4 <= e; j += 4) {
        int s0 = esrc[j], s1 = esrc[j + 1], s2 = esrc[j + 2], s3 = esrc[j + 3];
        float a0 = dinv[s0] * ddst, a1 = dinv[s1] * ddst;
        float a2 = dinv[s2] * ddst, a3 = dinv[s3] * ddst;
        float4 x0 = *(const float4*)(H + (size_t)s0 * 256 + lane * 4);
        float4 x1 = *(const float4*)(H + (size_t)s1 * 256 + lane * 4);
        float4 x2 = *(const float4*)(H + (size_t)s2 * 256 + lane * 4);
        float4 x3 = *(const float4*)(H + (size_t)s3 * 256 + lane * 4);
        acc.x = fmaf(a0, x0.x, acc.x); acc.y = fmaf(a0, x0.y, acc.y);
        acc.z = fmaf(a0, x0.z, acc.z); acc.w = fmaf(a0, x0.w, acc.w);
        acc.x = fmaf(a1, x1.x, acc.x); acc.y = fmaf(a1, x1.y, acc.y);
        acc.z = fmaf(a1, x1.z, acc.z); acc.w = fmaf(a1, x1.w, acc.w);
        acc.x = fmaf(a2, x2.x, acc.x); acc.y = fmaf(a2, x2.y, acc.y);
        acc.z = fmaf(a2, x2.z, acc.z); acc.w = fmaf(a2, x2.w, acc.w);
        acc.x = fmaf(a3, x3.x, acc.x); acc.y = fmaf(a3, x3.y, acc.y);
        acc.z = fmaf(a3, x3.z, acc.z); acc.w = fmaf(a3, x3.w, acc.w);
    }
    for (; j < e; j++) {
        int src = esrc[j];
        float w = dinv[src] * ddst;
        float4 x = *(const float4*)(H + (size_t)src * 256 + lane * 4);
        acc.x = fmaf(w, x.x, acc.x); acc.y = fmaf(w, x.y, acc.y);
        acc.z = fmaf(w, x.z, acc.z); acc.w = fmaf(w, x.w, acc.w);
    }
    *(float4*)(out + (size_t)node * 256 + lane * 4) = acc;
}

// ---------------- SGEMM + bias + relu: C[M,256] = relu(A[M,K] @ B[K,256] + b) --------
// 128x128 tile, 256 threads, 8x8 micro-tile
template <int K>
__launch_bounds__(256, 2)
__global__ void sgemm_bias_relu(const float* __restrict__ A, const float* __restrict__ B,
                                const float* __restrict__ bias, float* __restrict__ C,
                                int M) {
    const int N = 256;
    __shared__ float As[16][128];  // [k][m]
    __shared__ float Bs[16][128];  // [k][n]

    int tid = threadIdx.x;
    int tx = tid & 15;   // col group
    int ty = tid >> 4;   // row group
    int bm = blockIdx.x * 128;
    int bn = blockIdx.y * 128;

    float acc[8][8];
#pragma unroll
    for (int i = 0; i < 8; i++)
#pragma unroll
        for (int j = 0; j < 8; j++) acc[i][j] = 0.0f;

    for (int k0 = 0; k0 < K; k0 += 16) {
#pragma unroll
        for (int i = 0; i < 2; i++) {
            int idx = tid * 2 + i;           // 0..511
            // A tile: 128 rows x 16 k
            int row = idx >> 2;              // 0..127
            int kg = (idx & 3) * 4;          // 0,4,8,12
            float4 v = make_float4(0.f, 0.f, 0.f, 0.f);
            int gm = bm + row;
            if (gm < M) v = *(const float4*)(A + (size_t)gm * K + k0 + kg);
            As[kg + 0][row] = v.x;
            As[kg + 1][row] = v.y;
            As[kg + 2][row] = v.z;
            As[kg + 3][row] = v.w;
            // B tile: 16 k x 128 n
            int brow = idx >> 5;             // 0..15
            int bcol = (idx & 31) * 4;       // 0..124
            *(float4*)&Bs[brow][bcol] =
                *(const float4*)(B + (size_t)(k0 + brow) * N + bn + bcol);
        }
        __syncthreads();

#pragma unroll
        for (int kk = 0; kk < 16; kk++) {
            float a[8], b[8];
            *(float4*)&a[0] = *(float4*)&As[kk][ty * 8];
            *(float4*)&a[4] = *(float4*)&As[kk][ty * 8 + 4];
            *(float4*)&b[0] = *(float4*)&Bs[kk][tx * 8];
            *(float4*)&b[4] = *(float4*)&Bs[kk][tx * 8 + 4];
#pragma unroll
            for (int i = 0; i < 8; i++)
#pragma unroll
                for (int j = 0; j < 8; j++) acc[i][j] = fmaf(a[i], b[j], acc[i][j]);
        }
        __syncthreads();
    }

    float bb[8];
    *(float4*)&bb[0] = *(const float4*)(bias + bn + tx * 8);
    *(float4*)&bb[4] = *(const float4*)(bias + bn + tx * 8 + 4);
#pragma unroll
    for (int i = 0; i < 8; i++) {
        int m = bm + ty * 8 + i;
        if (m < M) {
            float o[8];
#pragma unroll
            for (int j = 0; j < 8; j++) o[j] = fmaxf(acc[i][j] + bb[j], 0.f);
            *(float4*)(C + (size_t)m * N + bn + tx * 8) = *(float4*)&o[0];
            *(float4*)(C + (size_t)m * N + bn + tx * 8 + 4) = *(float4*)&o[4];
        }
    }
}

// ---------------- fused mean-pool (batch is sorted) + MLP head ----------------
__global__ __launch_bounds__(256) void pool_mlp_kernel(const float* __restrict__ h,
                                                       const int* __restrict__ batch,
                                                       const float* __restrict__ Wf1,
                                                       const float* __restrict__ bf1,
                                                       const float* __restrict__ Wf2,
                                                       const float* __restrict__ bf2,
                                                       float* __restrict__ out) {
    int g = blockIdx.x;
    int t = threadIdx.x;  // 0..255
    __shared__ int bounds[2];
    if (t < 2) {
        int target = g + t;
        int lo = 0, hi = N_NODES;
        while (lo < hi) {
            int mid = (lo + hi) >> 1;
            if (batch[mid] < target) lo = mid + 1;
            else hi = mid;
        }
        bounds[t] = lo;
    }
    __syncthreads();
    int lo = bounds[0], hi = bounds[1];

    float acc = 0.f;
    for (int n = lo; n < hi; n++) acc += h[(size_t)n * HID + t];
    float inv = (hi > lo) ? 1.0f / (float)(hi - lo) : 0.f;
    __shared__ float p[256];
    p[t] = acc * inv;
    __syncthreads();

    float hv = 0.f;
    if (t < 128) {
        float a = bf1[t];
#pragma unroll 8
        for (int k = 0; k < 256; k++) a = fmaf(p[k], Wf1[k * 128 + t], a);
        hv = fmaxf(a, 0.f) * Wf2[t];
    }
#pragma unroll
    for (int off = 32; off > 0; off >>= 1) hv += __shfl_down(hv, off, 64);
    __shared__ float partial[4];
    if ((t & 63) == 0) partial[t >> 6] = hv;
    __syncthreads();
    if (t == 0) out[g] = partial[0] + partial[1] + bf2[0];
}

extern "C" void kernel_launch(void* const* d_in, const int* in_sizes, int n_in,
                              void* d_out, int out_size, void* d_ws, size_t ws_size,
                              hipStream_t stream) {
    const float* x   = (const float*)d_in[0];
    const int*   ei  = (const int*)d_in[1];
    const int*   bat = (const int*)d_in[2];
    const float* W1  = (const float*)d_in[3];
    const float* b1  = (const float*)d_in[4];
    const float* W2  = (const float*)d_in[5];
    const float* b2  = (const float*)d_in[6];
    const float* Wf1 = (const float*)d_in[7];
    const float* bf1 = (const float*)d_in[8];
    const float* Wf2 = (const float*)d_in[9];
    const float* bf2 = (const float*)d_in[10];
    float* out = (float*)d_out;

    char* ws = (char*)d_ws;
    // layout:
    //   0x0000000: deg    (100000 int)
    //   0x0080000: dinv   (100000 f32)
    //   0x0100000: rowptr (100001 int)
    //   0x0180000: fill   (100000 int)
    //   0x0200000: esrc   (1.6M int)
    //   0x0900000: bufA   (100000*256 f32 = 0x61A8000 B)
    //   0x6AA8000: bufB   (same)
    int*   deg    = (int*)(ws);
    float* dinv   = (float*)(ws + 0x0080000);
    int*   rowptr = (int*)(ws + 0x0100000);
    int*   fill   = (int*)(ws + 0x0180000);
    int*   esrc   = (int*)(ws + 0x0200000);
    float* bufA   = (float*)(ws + 0x0900000);
    float* bufB   = (float*)(ws + 0x6AA8000);

    hipMemsetAsync(deg, 0, (size_t)N_NODES * sizeof(int), stream);
    hipMemsetAsync(fill, 0, (size_t)N_NODES * sizeof(int), stream);

    // CSR build
    count_deg_kernel<<<(N_EDGES + 255) / 256, 256, 0, stream>>>(ei, deg);
    dinv_kernel<<<(N_NODES + 255) / 256, 256, 0, stream>>>(deg, dinv);
    scan_kernel<<<1, 1024, 0, stream>>>(deg, rowptr);
    fill_kernel<<<(N_EDGES + 255) / 256, 256, 0, stream>>>(ei, rowptr, fill, esrc);

    // layer 1: aggX = A~ x   (128-dim), then H1 = relu(aggX @ W1 + b1)
    agg128_kernel<<<N_NODES / 4, 256, 0, stream>>>(x, esrc, rowptr, dinv, bufA);
    {
        dim3 grid((N_NODES + 127) / 128, 2);
        sgemm_bias_relu<IN_DIM><<<grid, 256, 0, stream>>>(bufA, W1, b1, bufB, N_NODES);
    }

    // layer 2: aggH = A~ H1  (256-dim), then H2 = relu(aggH @ W2 + b2)
    agg256_kernel<<<N_NODES / 4, 256, 0, stream>>>(bufB, esrc, rowptr, dinv, bufA);
    {
        dim3 grid((N_NODES + 127) / 128, 2);
        sgemm_bias_relu<HID><<<grid, 256, 0, stream>>>(bufA, W2, b2, bufB, N_NODES);
    }

    // pooling + MLP head
    pool_mlp_kernel<<<NUM_GRAPHS, 256, 0, stream>>>(bufB, bat, Wf1, bf1, Wf2, bf2, out);
}

// Round 4
// 940.882 us; speedup vs baseline: 12.2599x; 1.1504x over previous
//
#include <hip/hip_runtime.h>
#include <hip/hip_bf16.h>

#define N_NODES 100000
#define N_EDGES 1600000
#define IN_DIM 128
#define HID 256
#define NUM_GRAPHS 2048
#define M_PAD 100096  // 782 * 128

typedef __bf16 bf16x8 __attribute__((ext_vector_type(8)));
typedef float f32x4 __attribute__((ext_vector_type(4)));

__device__ inline unsigned short f2bf(float x) {
    union { __hip_bfloat16 h; unsigned short u; } v;
    v.h = __float2bfloat16(x);
    return v.u;
}
__device__ inline float bf2f(unsigned short u) {
    return __uint_as_float(((unsigned int)u) << 16);
}

// ---------------- degree histogram over dst ----------------
__global__ void count_deg_kernel(const int* __restrict__ ei, int* __restrict__ deg) {
    int e = blockIdx.x * blockDim.x + threadIdx.x;
    if (e < N_EDGES) {
        atomicAdd(&deg[ei[N_EDGES + e]], 1);
    }
}

__global__ void dinv_kernel(const int* __restrict__ deg, float* __restrict__ dinv) {
    int n = blockIdx.x * blockDim.x + threadIdx.x;
    if (n < N_NODES) {
        dinv[n] = rsqrtf((float)(deg[n] + 1));  // self-loop adds 1
    }
}

// ---------------- exclusive prefix sum over deg -> rowptr[N+1] ----------------
__global__ __launch_bounds__(1024) void scan_kernel(const int* __restrict__ deg,
                                                    int* __restrict__ rowptr) {
    const int C = (N_NODES + 1023) / 1024;  // 98
    int t = threadIdx.x;
    int start = t * C;
    int end = min(start + C, N_NODES);
    int sum = 0;
    for (int i = start; i < end; i++) sum += deg[i];
    __shared__ int sdata[1024];
    sdata[t] = sum;
    __syncthreads();
    for (int off = 1; off < 1024; off <<= 1) {
        int x = (t >= off) ? sdata[t - off] : 0;
        __syncthreads();
        sdata[t] += x;
        __syncthreads();
    }
    int run = (t > 0) ? sdata[t - 1] : 0;
    for (int i = start; i < end; i++) {
        rowptr[i] = run;
        run += deg[i];
    }
    if (t == 1023) rowptr[N_NODES] = run;
}

// ---------------- bucket fill: CSR src list sorted by dst ----------------
__global__ void fill_kernel(const int* __restrict__ ei, const int* __restrict__ rowptr,
                            int* __restrict__ fill, int* __restrict__ esrc) {
    int e = blockIdx.x * blockDim.x + threadIdx.x;
    if (e < N_EDGES) {
        int dst = ei[N_EDGES + e];
        int pos = rowptr[dst] + atomicAdd(&fill[dst], 1);
        esrc[pos] = ei[e];
    }
}

// ---------------- weight transpose + bf16 split: W[K][256] -> Wt_hi/lo[256][K] -----
template <int K>
__global__ void wsplit_kernel(const float* __restrict__ W, unsigned short* __restrict__ Wth,
                              unsigned short* __restrict__ Wtl) {
    int idx = blockIdx.x * 256 + threadIdx.x;
    if (idx >= K * 256) return;
    int k = idx >> 8, n = idx & 255;
    float w = W[idx];
    unsigned short h = f2bf(w);
    unsigned short l = f2bf(w - bf2f(h));
    Wth[n * K + k] = h;
    Wtl[n * K + k] = l;
}

// ---------------- gather agg 128-dim, writes bf16 hi/lo split ----------------
__global__ __launch_bounds__(256) void agg128_kernel(const float* __restrict__ H,
                                                     const int* __restrict__ esrc,
                                                     const int* __restrict__ rowptr,
                                                     const float* __restrict__ dinv,
                                                     unsigned short* __restrict__ Ah,
                                                     unsigned short* __restrict__ Al) {
    int node = blockIdx.x * 4 + (threadIdx.x >> 6);
    int lane = threadIdx.x & 63;
    if (node >= N_NODES) return;
    float ddst = dinv[node];
    int s = rowptr[node], e = rowptr[node + 1];

    float w0 = ddst * ddst;
    float2 h0 = *(const float2*)(H + (size_t)node * 128 + lane * 2);
    float2 acc = make_float2(w0 * h0.x, w0 * h0.y);

    int j = s;
    for (; j + 4 <= e; j += 4) {
        int s0 = esrc[j], s1 = esrc[j + 1], s2 = esrc[j + 2], s3 = esrc[j + 3];
        float a0 = dinv[s0] * ddst, a1 = dinv[s1] * ddst;
        float a2 = dinv[s2] * ddst, a3 = dinv[s3] * ddst;
        float2 x0 = *(const float2*)(H + (size_t)s0 * 128 + lane * 2);
        float2 x1 = *(const float2*)(H + (size_t)s1 * 128 + lane * 2);
        float2 x2 = *(const float2*)(H + (size_t)s2 * 128 + lane * 2);
        float2 x3 = *(const float2*)(H + (size_t)s3 * 128 + lane * 2);
        acc.x = fmaf(a0, x0.x, acc.x); acc.y = fmaf(a0, x0.y, acc.y);
        acc.x = fmaf(a1, x1.x, acc.x); acc.y = fmaf(a1, x1.y, acc.y);
        acc.x = fmaf(a2, x2.x, acc.x); acc.y = fmaf(a2, x2.y, acc.y);
        acc.x = fmaf(a3, x3.x, acc.x); acc.y = fmaf(a3, x3.y, acc.y);
    }
    for (; j < e; j++) {
        int src = esrc[j];
        float w = dinv[src] * ddst;
        float2 x = *(const float2*)(H + (size_t)src * 128 + lane * 2);
        acc.x = fmaf(w, x.x, acc.x);
        acc.y = fmaf(w, x.y, acc.y);
    }
    size_t o = (size_t)node * 128 + lane * 2;
    ushort2 hi, lo;
    hi.x = f2bf(acc.x); lo.x = f2bf(acc.x - bf2f(hi.x));
    hi.y = f2bf(acc.y); lo.y = f2bf(acc.y - bf2f(hi.y));
    *(ushort2*)(Ah + o) = hi;
    *(ushort2*)(Al + o) = lo;
}

// ---------------- gather agg 256-dim, writes bf16 hi/lo split ----------------
__global__ __launch_bounds__(256) void agg256_kernel(const float* __restrict__ H,
                                                     const int* __restrict__ esrc,
                                                     const int* __restrict__ rowptr,
                                                     const float* __restrict__ dinv,
                                                     unsigned short* __restrict__ Ah,
                                                     unsigned short* __restrict__ Al) {
    int node = blockIdx.x * 4 + (threadIdx.x >> 6);
    int lane = threadIdx.x & 63;
    if (node >= N_NODES) return;
    float ddst = dinv[node];
    int s = rowptr[node], e = rowptr[node + 1];

    float w0 = ddst * ddst;
    float4 h0 = *(const float4*)(H + (size_t)node * 256 + lane * 4);
    float4 acc = make_float4(w0 * h0.x, w0 * h0.y, w0 * h0.z, w0 * h0.w);

    int j = s;
    for (; j + 4 <= e; j += 4) {
        int s0 = esrc[j], s1 = esrc[j + 1], s2 = esrc[j + 2], s3 = esrc[j + 3];
        float a0 = dinv[s0] * ddst, a1 = dinv[s1] * ddst;
        float a2 = dinv[s2] * ddst, a3 = dinv[s3] * ddst;
        float4 x0 = *(const float4*)(H + (size_t)s0 * 256 + lane * 4);
        float4 x1 = *(const float4*)(H + (size_t)s1 * 256 + lane * 4);
        float4 x2 = *(const float4*)(H + (size_t)s2 * 256 + lane * 4);
        float4 x3 = *(const float4*)(H + (size_t)s3 * 256 + lane * 4);
        acc.x = fmaf(a0, x0.x, acc.x); acc.y = fmaf(a0, x0.y, acc.y);
        acc.z = fmaf(a0, x0.z, acc.z); acc.w = fmaf(a0, x0.w, acc.w);
        acc.x = fmaf(a1, x1.x, acc.x); acc.y = fmaf(a1, x1.y, acc.y);
        acc.z = fmaf(a1, x1.z, acc.z); acc.w = fmaf(a1, x1.w, acc.w);
        acc.x = fmaf(a2, x2.x, acc.x); acc.y = fmaf(a2, x2.y, acc.y);
        acc.z = fmaf(a2, x2.z, acc.z); acc.w = fmaf(a2, x2.w, acc.w);
        acc.x = fmaf(a3, x3.x, acc.x); acc.y = fmaf(a3, x3.y, acc.y);
        acc.z = fmaf(a3, x3.z, acc.z); acc.w = fmaf(a3, x3.w, acc.w);
    }
    for (; j < e; j++) {
        int src = esrc[j];
        float w = dinv[src] * ddst;
        float4 x = *(const float4*)(H + (size_t)src * 256 + lane * 4);
        acc.x = fmaf(w, x.x, acc.x); acc.y = fmaf(w, x.y, acc.y);
        acc.z = fmaf(w, x.z, acc.z); acc.w = fmaf(w, x.w, acc.w);
    }
    size_t o = (size_t)node * 256 + lane * 4;
    ushort4 hi, lo;
    hi.x = f2bf(acc.x); lo.x = f2bf(acc.x - bf2f(hi.x));
    hi.y = f2bf(acc.y); lo.y = f2bf(acc.y - bf2f(hi.y));
    hi.z = f2bf(acc.z); lo.z = f2bf(acc.z - bf2f(hi.z));
    hi.w = f2bf(acc.w); lo.w = f2bf(acc.w - bf2f(hi.w));
    *(ushort4*)(Ah + o) = hi;
    *(ushort4*)(Al + o) = lo;
}

// ---------------- MFMA bf16x3 GEMM: C = relu(A @ W + b), A=Ah+Al, W=Wh+Wl ----------
// 128x128 tile, 256 thr (4 waves 2x2), 16x16x32 mfma, wave tile 64x64.
// A: [M_PAD][K] bf16 (hi/lo), Wt: [256][K] bf16 (hi/lo, pre-transposed), C: [M][256] f32
template <int K>
__launch_bounds__(256, 2)
__global__ void mfma_gemm_bias_relu(const unsigned short* __restrict__ Ah,
                                    const unsigned short* __restrict__ Al,
                                    const unsigned short* __restrict__ Bh,
                                    const unsigned short* __restrict__ Bl,
                                    const float* __restrict__ bias,
                                    float* __restrict__ C) {
    __shared__ __align__(16) unsigned short lds[4 * 128 * 32];
    unsigned short* Ahs = lds;
    unsigned short* Als = lds + 4096;
    unsigned short* Bhs = lds + 8192;
    unsigned short* Bls = lds + 12288;

    int tid = threadIdx.x;
    int bm = blockIdx.x * 128;
    int bn = blockIdx.y * 128;
    int wid = tid >> 6, lane = tid & 63;
    int wm = wid & 1, wn = wid >> 1;
    int lrow = lane & 15, quad = lane >> 4;

    f32x4 acc[4][4];
#pragma unroll
    for (int mi = 0; mi < 4; mi++)
#pragma unroll
        for (int ni = 0; ni < 4; ni++) acc[mi][ni] = (f32x4){0.f, 0.f, 0.f, 0.f};

    for (int k0 = 0; k0 < K; k0 += 32) {
        // stage 4 tiles of [128 rows][32 k] bf16 (8 KB each); 16B chunks per thread
#pragma unroll
        for (int i = 0; i < 8; i++) {
            int c = tid + 256 * i;
            int tile = c >> 9;         // 0..3
            int w = c & 511;           // chunk within tile
            int row = w >> 2;          // 0..127
            int part = w & 3;          // 16B quarter of the 64B row-slice
            const unsigned short* g;
            if (tile == 0)      g = Ah + (size_t)(bm + row) * K + k0 + part * 8;
            else if (tile == 1) g = Al + (size_t)(bm + row) * K + k0 + part * 8;
            else if (tile == 2) g = Bh + (size_t)(bn + row) * K + k0 + part * 8;
            else                g = Bl + (size_t)(bn + row) * K + k0 + part * 8;
            ulonglong2 v = *(const ulonglong2*)g;
            *(ulonglong2*)&lds[(tile << 12) + row * 32 + part * 8] = v;
        }
        __syncthreads();

        bf16x8 ah[4], al[4], bh[4], bl[4];
#pragma unroll
        for (int mi = 0; mi < 4; mi++) {
            int r = wm * 64 + mi * 16 + lrow;
            ah[mi] = *(const bf16x8*)&Ahs[r * 32 + quad * 8];
            al[mi] = *(const bf16x8*)&Als[r * 32 + quad * 8];
        }
#pragma unroll
        for (int ni = 0; ni < 4; ni++) {
            int r = wn * 64 + ni * 16 + lrow;
            bh[ni] = *(const bf16x8*)&Bhs[r * 32 + quad * 8];
            bl[ni] = *(const bf16x8*)&Bls[r * 32 + quad * 8];
        }
#pragma unroll
        for (int mi = 0; mi < 4; mi++)
#pragma unroll
            for (int ni = 0; ni < 4; ni++) {
                acc[mi][ni] = __builtin_amdgcn_mfma_f32_16x16x32_bf16(ah[mi], bh[ni], acc[mi][ni], 0, 0, 0);
                acc[mi][ni] = __builtin_amdgcn_mfma_f32_16x16x32_bf16(ah[mi], bl[ni], acc[mi][ni], 0, 0, 0);
                acc[mi][ni] = __builtin_amdgcn_mfma_f32_16x16x32_bf16(al[mi], bh[ni], acc[mi][ni], 0, 0, 0);
            }
        __syncthreads();
    }

    // epilogue: bias + relu; C/D layout: col=lane&15, row=quad*4+reg
    float bv[4];
#pragma unroll
    for (int ni = 0; ni < 4; ni++) bv[ni] = bias[bn + wn * 64 + ni * 16 + lrow];
#pragma unroll
    for (int mi = 0; mi < 4; mi++) {
        int row0 = bm + wm * 64 + mi * 16 + quad * 4;
#pragma unroll
        for (int ni = 0; ni < 4; ni++) {
            int col = bn + wn * 64 + ni * 16 + lrow;
#pragma unroll
            for (int r = 0; r < 4; r++) {
                int row = row0 + r;
                if (row < N_NODES)
                    C[(size_t)row * 256 + col] = fmaxf(acc[mi][ni][r] + bv[ni], 0.f);
            }
        }
    }
}

// ---------------- fused mean-pool (batch sorted) + MLP head ----------------
__global__ __launch_bounds__(256) void pool_mlp_kernel(const float* __restrict__ h,
                                                       const int* __restrict__ batch,
                                                       const float* __restrict__ Wf1,
                                                       const float* __restrict__ bf1,
                                                       const float* __restrict__ Wf2,
                                                       const float* __restrict__ bf2,
                                                       float* __restrict__ out) {
    int g = blockIdx.x;
    int t = threadIdx.x;  // 0..255
    __shared__ int bounds[2];
    if (t < 2) {
        int target = g + t;
        int lo = 0, hi = N_NODES;
        while (lo < hi) {
            int mid = (lo + hi) >> 1;
            if (batch[mid] < target) lo = mid + 1;
            else hi = mid;
        }
        bounds[t] = lo;
    }
    __syncthreads();
    int lo = bounds[0], hi = bounds[1];

    float acc = 0.f;
    for (int n = lo; n < hi; n++) acc += h[(size_t)n * HID + t];
    float inv = (hi > lo) ? 1.0f / (float)(hi - lo) : 0.f;
    __shared__ float p[256];
    p[t] = acc * inv;
    __syncthreads();

    float hv = 0.f;
    if (t < 128) {
        float a = bf1[t];
#pragma unroll 8
        for (int k = 0; k < 256; k++) a = fmaf(p[k], Wf1[k * 128 + t], a);
        hv = fmaxf(a, 0.f) * Wf2[t];
    }
#pragma unroll
    for (int off = 32; off > 0; off >>= 1) hv += __shfl_down(hv, off, 64);
    __shared__ float partial[4];
    if ((t & 63) == 0) partial[t >> 6] = hv;
    __syncthreads();
    if (t == 0) out[g] = partial[0] + partial[1] + bf2[0];
}

extern "C" void kernel_launch(void* const* d_in, const int* in_sizes, int n_in,
                              void* d_out, int out_size, void* d_ws, size_t ws_size,
                              hipStream_t stream) {
    const float* x   = (const float*)d_in[0];
    const int*   ei  = (const int*)d_in[1];
    const int*   bat = (const int*)d_in[2];
    const float* W1  = (const float*)d_in[3];
    const float* b1  = (const float*)d_in[4];
    const float* W2  = (const float*)d_in[5];
    const float* b2  = (const float*)d_in[6];
    const float* Wf1 = (const float*)d_in[7];
    const float* bf1 = (const float*)d_in[8];
    const float* Wf2 = (const float*)d_in[9];
    const float* bf2 = (const float*)d_in[10];
    float* out = (float*)d_out;

    char* ws = (char*)d_ws;
    // layout (total 0xCC18000 = 214.07 MB, under proven 214.3 MB):
    //   0x0000000 deg        0x0080000 dinv      0x0100000 rowptr   0x0180000 fill
    //   0x0200000 esrc (6.4 MB)
    //   0x0820000 W1t_hi     0x0830000 W1t_lo    0x0840000 W2t_hi   0x0860000 W2t_lo
    //   0x0880000 A1_hi (25.6 MB)   0x2100000 A1_lo
    //   0x0880000 A2_hi (51.2 MB, reuses dead A1)   0x3980000 A2_lo
    //   0x6A70000 bufC (102.4 MB, C1 then C2)
    int*   deg    = (int*)(ws);
    float* dinv   = (float*)(ws + 0x0080000);
    int*   rowptr = (int*)(ws + 0x0100000);
    int*   fill   = (int*)(ws + 0x0180000);
    int*   esrc   = (int*)(ws + 0x0200000);
    unsigned short* W1th = (unsigned short*)(ws + 0x0820000);
    unsigned short* W1tl = (unsigned short*)(ws + 0x0830000);
    unsigned short* W2th = (unsigned short*)(ws + 0x0840000);
    unsigned short* W2tl = (unsigned short*)(ws + 0x0860000);
    unsigned short* A1h  = (unsigned short*)(ws + 0x0880000);
    unsigned short* A1l  = (unsigned short*)(ws + 0x2100000);
    unsigned short* A2h  = (unsigned short*)(ws + 0x0880000);
    unsigned short* A2l  = (unsigned short*)(ws + 0x3980000);
    float* bufC = (float*)(ws + 0x6A70000);

    hipMemsetAsync(deg, 0, (size_t)N_NODES * sizeof(int), stream);
    hipMemsetAsync(fill, 0, (size_t)N_NODES * sizeof(int), stream);

    // weight split (independent of CSR)
    wsplit_kernel<IN_DIM><<<(IN_DIM * 256) / 256, 256, 0, stream>>>(W1, W1th, W1tl);
    wsplit_kernel<HID><<<(HID * 256) / 256, 256, 0, stream>>>(W2, W2th, W2tl);

    // CSR build
    count_deg_kernel<<<(N_EDGES + 255) / 256, 256, 0, stream>>>(ei, deg);
    dinv_kernel<<<(N_NODES + 255) / 256, 256, 0, stream>>>(deg, dinv);
    scan_kernel<<<1, 1024, 0, stream>>>(deg, rowptr);
    fill_kernel<<<(N_EDGES + 255) / 256, 256, 0, stream>>>(ei, rowptr, fill, esrc);

    // layer 1: A1 = split(A~ x); C1 = relu(A1 @ W1 + b1)
    agg128_kernel<<<N_NODES / 4, 256, 0, stream>>>(x, esrc, rowptr, dinv, A1h, A1l);
    {
        dim3 grid(M_PAD / 128, 2);
        mfma_gemm_bias_relu<IN_DIM><<<grid, 256, 0, stream>>>(A1h, A1l, W1th, W1tl, b1, bufC);
    }

    // layer 2: A2 = split(A~ C1); C2 = relu(A2 @ W2 + b2)
    agg256_kernel<<<N_NODES / 4, 256, 0, stream>>>(bufC, esrc, rowptr, dinv, A2h, A2l);
    {
        dim3 grid(M_PAD / 128, 2);
        mfma_gemm_bias_relu<HID><<<grid, 256, 0, stream>>>(A2h, A2l, W2th, W2tl, b2, bufC);
    }

    // pooling + MLP head
    pool_mlp_kernel<<<NUM_GRAPHS, 256, 0, stream>>>(bufC, bat, Wf1, bf1, Wf2, bf2, out);
}

// Round 5
// 790.733 us; speedup vs baseline: 14.5879x; 1.1899x over previous
//
#include <hip/hip_runtime.h>
#include <hip/hip_bf16.h>

#define N_NODES 100000
#define N_EDGES 1600000
#define IN_DIM 128
#define HID 256
#define NUM_GRAPHS 2048
#define M_PAD 100096  // 782 * 128

typedef __bf16 bf16x8 __attribute__((ext_vector_type(8)));
typedef float f32x4 __attribute__((ext_vector_type(4)));

__device__ inline unsigned short f2bf(float x) {
    union { __hip_bfloat16 h; unsigned short u; } v;
    v.h = __float2bfloat16(x);
    return v.u;
}
__device__ inline float bf2f(unsigned short u) {
    return __uint_as_float(((unsigned int)u) << 16);
}

// ---------------- degree histogram over dst ----------------
__global__ void count_deg_kernel(const int* __restrict__ ei, int* __restrict__ deg) {
    int e = blockIdx.x * blockDim.x + threadIdx.x;
    if (e < N_EDGES) {
        atomicAdd(&deg[ei[N_EDGES + e]], 1);
    }
}

__global__ void dinv_kernel(const int* __restrict__ deg, float* __restrict__ dinv) {
    int n = blockIdx.x * blockDim.x + threadIdx.x;
    if (n < N_NODES) {
        dinv[n] = rsqrtf((float)(deg[n] + 1));  // self-loop adds 1
    }
}

// ---------------- exclusive prefix sum over deg -> rowptr[N+1] ----------------
__global__ __launch_bounds__(1024) void scan_kernel(const int* __restrict__ deg,
                                                    int* __restrict__ rowptr) {
    const int C = (N_NODES + 1023) / 1024;  // 98
    int t = threadIdx.x;
    int start = t * C;
    int end = min(start + C, N_NODES);
    int sum = 0;
    for (int i = start; i < end; i++) sum += deg[i];
    __shared__ int sdata[1024];
    sdata[t] = sum;
    __syncthreads();
    for (int off = 1; off < 1024; off <<= 1) {
        int x = (t >= off) ? sdata[t - off] : 0;
        __syncthreads();
        sdata[t] += x;
        __syncthreads();
    }
    int run = (t > 0) ? sdata[t - 1] : 0;
    for (int i = start; i < end; i++) {
        rowptr[i] = run;
        run += deg[i];
    }
    if (t == 1023) rowptr[N_NODES] = run;
}

// ---------------- bucket fill: CSR src list sorted by dst ----------------
__global__ void fill_kernel(const int* __restrict__ ei, const int* __restrict__ rowptr,
                            int* __restrict__ fill, int* __restrict__ esrc) {
    int e = blockIdx.x * blockDim.x + threadIdx.x;
    if (e < N_EDGES) {
        int dst = ei[N_EDGES + e];
        int pos = rowptr[dst] + atomicAdd(&fill[dst], 1);
        esrc[pos] = ei[e];
    }
}

// ---------------- x -> bf16 ----------------
__global__ void x2bf_kernel(const float* __restrict__ x, unsigned short* __restrict__ xb) {
    size_t i = ((size_t)blockIdx.x * 256 + threadIdx.x) * 4;
    float4 v = *(const float4*)(x + i);
    ushort4 o;
    o.x = f2bf(v.x); o.y = f2bf(v.y); o.z = f2bf(v.z); o.w = f2bf(v.w);
    *(ushort4*)(xb + i) = o;
}

// ---------------- weight transpose + bf16 split: W[K][256] -> Wt_hi/lo[256][K] -----
template <int K>
__global__ void wsplit_kernel(const float* __restrict__ W, unsigned short* __restrict__ Wth,
                              unsigned short* __restrict__ Wtl) {
    int idx = blockIdx.x * 256 + threadIdx.x;
    if (idx >= K * 256) return;
    int k = idx >> 8, n = idx & 255;
    float w = W[idx];
    unsigned short h = f2bf(w);
    unsigned short l = f2bf(w - bf2f(h));
    Wth[n * K + k] = h;
    Wtl[n * K + k] = l;
}

// ---------------- gather agg 128-dim from bf16, writes bf16 hi/lo split ----------
__global__ __launch_bounds__(256) void agg128_kernel(const unsigned short* __restrict__ X,
                                                     const int* __restrict__ esrc,
                                                     const int* __restrict__ rowptr,
                                                     const float* __restrict__ dinv,
                                                     unsigned short* __restrict__ Ah,
                                                     unsigned short* __restrict__ Al) {
    int node = blockIdx.x * 4 + (threadIdx.x >> 6);
    int lane = threadIdx.x & 63;
    if (node >= N_NODES) return;
    float ddst = dinv[node];
    int s = rowptr[node], e = rowptr[node + 1];

    float w0 = ddst * ddst;
    ushort2 h0 = *(const ushort2*)(X + (size_t)node * 128 + lane * 2);
    float2 acc = make_float2(w0 * bf2f(h0.x), w0 * bf2f(h0.y));

    int j = s;
    for (; j + 8 <= e; j += 8) {
        int si[8];
#pragma unroll
        for (int u = 0; u < 8; u++) si[u] = esrc[j + u];
        ushort2 xv[8];
#pragma unroll
        for (int u = 0; u < 8; u++)
            xv[u] = *(const ushort2*)(X + (size_t)si[u] * 128 + lane * 2);
        float a[8];
#pragma unroll
        for (int u = 0; u < 8; u++) a[u] = dinv[si[u]] * ddst;
#pragma unroll
        for (int u = 0; u < 8; u++) {
            acc.x = fmaf(a[u], bf2f(xv[u].x), acc.x);
            acc.y = fmaf(a[u], bf2f(xv[u].y), acc.y);
        }
    }
    for (; j < e; j++) {
        int src = esrc[j];
        float w = dinv[src] * ddst;
        ushort2 xv = *(const ushort2*)(X + (size_t)src * 128 + lane * 2);
        acc.x = fmaf(w, bf2f(xv.x), acc.x);
        acc.y = fmaf(w, bf2f(xv.y), acc.y);
    }
    size_t o = (size_t)node * 128 + lane * 2;
    ushort2 hi, lo;
    hi.x = f2bf(acc.x); lo.x = f2bf(acc.x - bf2f(hi.x));
    hi.y = f2bf(acc.y); lo.y = f2bf(acc.y - bf2f(hi.y));
    *(ushort2*)(Ah + o) = hi;
    *(ushort2*)(Al + o) = lo;
}

// ---------------- gather agg 256-dim from bf16, writes bf16 hi/lo split ----------
__global__ __launch_bounds__(256) void agg256_kernel(const unsigned short* __restrict__ H,
                                                     const int* __restrict__ esrc,
                                                     const int* __restrict__ rowptr,
                                                     const float* __restrict__ dinv,
                                                     unsigned short* __restrict__ Ah,
                                                     unsigned short* __restrict__ Al) {
    int node = blockIdx.x * 4 + (threadIdx.x >> 6);
    int lane = threadIdx.x & 63;
    if (node >= N_NODES) return;
    float ddst = dinv[node];
    int s = rowptr[node], e = rowptr[node + 1];

    float w0 = ddst * ddst;
    ushort4 h0 = *(const ushort4*)(H + (size_t)node * 256 + lane * 4);
    float4 acc = make_float4(w0 * bf2f(h0.x), w0 * bf2f(h0.y),
                             w0 * bf2f(h0.z), w0 * bf2f(h0.w));

    int j = s;
    for (; j + 8 <= e; j += 8) {
        int si[8];
#pragma unroll
        for (int u = 0; u < 8; u++) si[u] = esrc[j + u];
        ushort4 xv[8];
#pragma unroll
        for (int u = 0; u < 8; u++)
            xv[u] = *(const ushort4*)(H + (size_t)si[u] * 256 + lane * 4);
        float a[8];
#pragma unroll
        for (int u = 0; u < 8; u++) a[u] = dinv[si[u]] * ddst;
#pragma unroll
        for (int u = 0; u < 8; u++) {
            acc.x = fmaf(a[u], bf2f(xv[u].x), acc.x);
            acc.y = fmaf(a[u], bf2f(xv[u].y), acc.y);
            acc.z = fmaf(a[u], bf2f(xv[u].z), acc.z);
            acc.w = fmaf(a[u], bf2f(xv[u].w), acc.w);
        }
    }
    for (; j < e; j++) {
        int src = esrc[j];
        float w = dinv[src] * ddst;
        ushort4 xv = *(const ushort4*)(H + (size_t)src * 256 + lane * 4);
        acc.x = fmaf(w, bf2f(xv.x), acc.x);
        acc.y = fmaf(w, bf2f(xv.y), acc.y);
        acc.z = fmaf(w, bf2f(xv.z), acc.z);
        acc.w = fmaf(w, bf2f(xv.w), acc.w);
    }
    size_t o = (size_t)node * 256 + lane * 4;
    ushort4 hi, lo;
    hi.x = f2bf(acc.x); lo.x = f2bf(acc.x - bf2f(hi.x));
    hi.y = f2bf(acc.y); lo.y = f2bf(acc.y - bf2f(hi.y));
    hi.z = f2bf(acc.z); lo.z = f2bf(acc.z - bf2f(hi.z));
    hi.w = f2bf(acc.w); lo.w = f2bf(acc.w - bf2f(hi.w));
    *(ushort4*)(Ah + o) = hi;
    *(ushort4*)(Al + o) = lo;
}

// ---------------- MFMA bf16x3 GEMM: C = relu(A @ W + b) ----------
// 128x128 tile, 256 thr (4 waves 2x2), 16x16x32 mfma, wave tile 64x64.
// BF16OUT: store C as bf16 (ushort), else f32.
template <int K, bool BF16OUT>
__launch_bounds__(256, 2)
__global__ void mfma_gemm_bias_relu(const unsigned short* __restrict__ Ah,
                                    const unsigned short* __restrict__ Al,
                                    const unsigned short* __restrict__ Bh,
                                    const unsigned short* __restrict__ Bl,
                                    const float* __restrict__ bias,
                                    void* __restrict__ Cout) {
    __shared__ __align__(16) unsigned short lds[4 * 128 * 32];
    unsigned short* Ahs = lds;
    unsigned short* Als = lds + 4096;
    unsigned short* Bhs = lds + 8192;
    unsigned short* Bls = lds + 12288;

    int tid = threadIdx.x;
    int bm = blockIdx.x * 128;
    int bn = blockIdx.y * 128;
    int wid = tid >> 6, lane = tid & 63;
    int wm = wid & 1, wn = wid >> 1;
    int lrow = lane & 15, quad = lane >> 4;

    f32x4 acc[4][4];
#pragma unroll
    for (int mi = 0; mi < 4; mi++)
#pragma unroll
        for (int ni = 0; ni < 4; ni++) acc[mi][ni] = (f32x4){0.f, 0.f, 0.f, 0.f};

    for (int k0 = 0; k0 < K; k0 += 32) {
#pragma unroll
        for (int i = 0; i < 8; i++) {
            int c = tid + 256 * i;
            int tile = c >> 9;         // 0..3
            int w = c & 511;
            int row = w >> 2;          // 0..127
            int part = w & 3;          // 16B quarter of 64B row-slice
            const unsigned short* g;
            if (tile == 0)      g = Ah + (size_t)(bm + row) * K + k0 + part * 8;
            else if (tile == 1) g = Al + (size_t)(bm + row) * K + k0 + part * 8;
            else if (tile == 2) g = Bh + (size_t)(bn + row) * K + k0 + part * 8;
            else                g = Bl + (size_t)(bn + row) * K + k0 + part * 8;
            ulonglong2 v = *(const ulonglong2*)g;
            *(ulonglong2*)&lds[(tile << 12) + row * 32 + part * 8] = v;
        }
        __syncthreads();

        bf16x8 ah[4], al[4], bh[4], bl[4];
#pragma unroll
        for (int mi = 0; mi < 4; mi++) {
            int r = wm * 64 + mi * 16 + lrow;
            ah[mi] = *(const bf16x8*)&Ahs[r * 32 + quad * 8];
            al[mi] = *(const bf16x8*)&Als[r * 32 + quad * 8];
        }
#pragma unroll
        for (int ni = 0; ni < 4; ni++) {
            int r = wn * 64 + ni * 16 + lrow;
            bh[ni] = *(const bf16x8*)&Bhs[r * 32 + quad * 8];
            bl[ni] = *(const bf16x8*)&Bls[r * 32 + quad * 8];
        }
#pragma unroll
        for (int mi = 0; mi < 4; mi++)
#pragma unroll
            for (int ni = 0; ni < 4; ni++) {
                acc[mi][ni] = __builtin_amdgcn_mfma_f32_16x16x32_bf16(ah[mi], bh[ni], acc[mi][ni], 0, 0, 0);
                acc[mi][ni] = __builtin_amdgcn_mfma_f32_16x16x32_bf16(ah[mi], bl[ni], acc[mi][ni], 0, 0, 0);
                acc[mi][ni] = __builtin_amdgcn_mfma_f32_16x16x32_bf16(al[mi], bh[ni], acc[mi][ni], 0, 0, 0);
            }
        __syncthreads();
    }

    // epilogue: bias + relu; C/D layout: col=lane&15, row=quad*4+reg
    float bv[4];
#pragma unroll
    for (int ni = 0; ni < 4; ni++) bv[ni] = bias[bn + wn * 64 + ni * 16 + lrow];
#pragma unroll
    for (int mi = 0; mi < 4; mi++) {
        int row0 = bm + wm * 64 + mi * 16 + quad * 4;
#pragma unroll
        for (int ni = 0; ni < 4; ni++) {
            int col = bn + wn * 64 + ni * 16 + lrow;
#pragma unroll
            for (int r = 0; r < 4; r++) {
                int row = row0 + r;
                if (row < N_NODES) {
                    float v = fmaxf(acc[mi][ni][r] + bv[ni], 0.f);
                    if (BF16OUT)
                        ((unsigned short*)Cout)[(size_t)row * 256 + col] = f2bf(v);
                    else
                        ((float*)Cout)[(size_t)row * 256 + col] = v;
                }
            }
        }
    }
}

// ---------------- fused mean-pool (batch sorted) + MLP head ----------------
__global__ __launch_bounds__(256) void pool_mlp_kernel(const float* __restrict__ h,
                                                       const int* __restrict__ batch,
                                                       const float* __restrict__ Wf1,
                                                       const float* __restrict__ bf1,
                                                       const float* __restrict__ Wf2,
                                                       const float* __restrict__ bf2,
                                                       float* __restrict__ out) {
    int g = blockIdx.x;
    int t = threadIdx.x;  // 0..255
    __shared__ int bounds[2];
    if (t < 2) {
        int target = g + t;
        int lo = 0, hi = N_NODES;
        while (lo < hi) {
            int mid = (lo + hi) >> 1;
            if (batch[mid] < target) lo = mid + 1;
            else hi = mid;
        }
        bounds[t] = lo;
    }
    __syncthreads();
    int lo = bounds[0], hi = bounds[1];

    float acc = 0.f;
    for (int n = lo; n < hi; n++) acc += h[(size_t)n * HID + t];
    float inv = (hi > lo) ? 1.0f / (float)(hi - lo) : 0.f;
    __shared__ float p[256];
    p[t] = acc * inv;
    __syncthreads();

    float hv = 0.f;
    if (t < 128) {
        float a = bf1[t];
#pragma unroll 8
        for (int k = 0; k < 256; k++) a = fmaf(p[k], Wf1[k * 128 + t], a);
        hv = fmaxf(a, 0.f) * Wf2[t];
    }
#pragma unroll
    for (int off = 32; off > 0; off >>= 1) hv += __shfl_down(hv, off, 64);
    __shared__ float partial[4];
    if ((t & 63) == 0) partial[t >> 6] = hv;
    __syncthreads();
    if (t == 0) out[g] = partial[0] + partial[1] + bf2[0];
}

extern "C" void kernel_launch(void* const* d_in, const int* in_sizes, int n_in,
                              void* d_out, int out_size, void* d_ws, size_t ws_size,
                              hipStream_t stream) {
    const float* x   = (const float*)d_in[0];
    const int*   ei  = (const int*)d_in[1];
    const int*   bat = (const int*)d_in[2];
    const float* W1  = (const float*)d_in[3];
    const float* b1  = (const float*)d_in[4];
    const float* W2  = (const float*)d_in[5];
    const float* b2  = (const float*)d_in[6];
    const float* Wf1 = (const float*)d_in[7];
    const float* bf1 = (const float*)d_in[8];
    const float* Wf2 = (const float*)d_in[9];
    const float* bf2 = (const float*)d_in[10];
    float* out = (float*)d_out;

    char* ws = (char*)d_ws;
    // layout (time-multiplexed; peak end 0xCBE8000 = 213.9 MB, < proven 214.07 MB):
    //   0x0000000 deg        0x0080000 dinv      0x0100000 rowptr   0x0180000 fill
    //   0x0200000 esrc (6.4 MB)
    //   0x0820000 W1th  0x0830000 W1tl  0x0840000 W2th  0x0860000 W2tl
    //   steps 2-3: A1h @ 0x0880000 (0x1870000), A1l @ 0x20F0000 (0x1870000)
    //   steps 4-5: A2h @ 0x0880000 (0x30E0000), A2l @ 0x3960000 (0x30E0000)
    //   steps 1-2: xbf @ 0x6A40000 (0x1870000)   [dead before H1bf written]
    //   steps 3-4: H1bf @ 0x6A40000 (0x30E0000)  [dead before bufC written]
    //   steps 5-6: bufC @ 0x6A40000 (0x61A8000) -> ends 0xCBE8000
    int*   deg    = (int*)(ws);
    float* dinv   = (float*)(ws + 0x0080000);
    int*   rowptr = (int*)(ws + 0x0100000);
    int*   fill   = (int*)(ws + 0x0180000);
    int*   esrc   = (int*)(ws + 0x0200000);
    unsigned short* W1th = (unsigned short*)(ws + 0x0820000);
    unsigned short* W1tl = (unsigned short*)(ws + 0x0830000);
    unsigned short* W2th = (unsigned short*)(ws + 0x0840000);
    unsigned short* W2tl = (unsigned short*)(ws + 0x0860000);
    unsigned short* A1h  = (unsigned short*)(ws + 0x0880000);
    unsigned short* A1l  = (unsigned short*)(ws + 0x20F0000);
    unsigned short* A2h  = (unsigned short*)(ws + 0x0880000);
    unsigned short* A2l  = (unsigned short*)(ws + 0x3960000);
    unsigned short* xbf  = (unsigned short*)(ws + 0x6A40000);
    unsigned short* H1bf = (unsigned short*)(ws + 0x6A40000);
    float* bufC = (float*)(ws + 0x6A40000);

    hipMemsetAsync(deg, 0, (size_t)N_NODES * sizeof(int), stream);
    hipMemsetAsync(fill, 0, (size_t)N_NODES * sizeof(int), stream);

    // independent prep
    x2bf_kernel<<<(N_NODES * IN_DIM / 4) / 256, 256, 0, stream>>>(x, xbf);
    wsplit_kernel<IN_DIM><<<(IN_DIM * 256) / 256, 256, 0, stream>>>(W1, W1th, W1tl);
    wsplit_kernel<HID><<<(HID * 256) / 256, 256, 0, stream>>>(W2, W2th, W2tl);

    // CSR build
    count_deg_kernel<<<(N_EDGES + 255) / 256, 256, 0, stream>>>(ei, deg);
    dinv_kernel<<<(N_NODES + 255) / 256, 256, 0, stream>>>(deg, dinv);
    scan_kernel<<<1, 1024, 0, stream>>>(deg, rowptr);
    fill_kernel<<<(N_EDGES + 255) / 256, 256, 0, stream>>>(ei, rowptr, fill, esrc);

    // layer 1: A1 = split(A~ x_bf16); H1bf = bf16(relu(A1 @ W1 + b1))
    agg128_kernel<<<N_NODES / 4, 256, 0, stream>>>(xbf, esrc, rowptr, dinv, A1h, A1l);
    {
        dim3 grid(M_PAD / 128, 2);
        mfma_gemm_bias_relu<IN_DIM, true><<<grid, 256, 0, stream>>>(A1h, A1l, W1th, W1tl, b1, H1bf);
    }

    // layer 2: A2 = split(A~ H1bf); C2 = relu(A2 @ W2 + b2) f32
    agg256_kernel<<<N_NODES / 4, 256, 0, stream>>>(H1bf, esrc, rowptr, dinv, A2h, A2l);
    {
        dim3 grid(M_PAD / 128, 2);
        mfma_gemm_bias_relu<HID, false><<<grid, 256, 0, stream>>>(A2h, A2l, W2th, W2tl, b2, bufC);
    }

    // pooling + MLP head
    pool_mlp_kernel<<<NUM_GRAPHS, 256, 0, stream>>>(bufC, bat, Wf1, bf1, Wf2, bf2, out);
}

// Round 6
// 641.950 us; speedup vs baseline: 17.9689x; 1.2318x over previous
//
#include <hip/hip_runtime.h>
#include <hip/hip_bf16.h>

#define N_NODES 100000
#define N_EDGES 1600000
#define IN_DIM 128
#define HID 256
#define NUM_GRAPHS 2048
#define M_PAD 100096  // 782 * 128
#define SCAN_BLOCKS 98  // ceil(100000/1024)

typedef __bf16 bf16x8 __attribute__((ext_vector_type(8)));
typedef float f32x4 __attribute__((ext_vector_type(4)));

__device__ inline unsigned short f2bf(float x) {
    union { __hip_bfloat16 h; unsigned short u; } v;
    v.h = __float2bfloat16(x);
    return v.u;
}
__device__ inline float bf2f(unsigned short u) {
    return __uint_as_float(((unsigned int)u) << 16);
}

// ---------------- degree histogram over dst ----------------
__global__ void count_deg_kernel(const int* __restrict__ ei, int* __restrict__ deg) {
    int e = blockIdx.x * blockDim.x + threadIdx.x;
    if (e < N_EDGES) {
        atomicAdd(&deg[ei[N_EDGES + e]], 1);
    }
}

__global__ void dinv_kernel(const int* __restrict__ deg, float* __restrict__ dinv) {
    int n = blockIdx.x * blockDim.x + threadIdx.x;
    if (n < N_NODES) {
        dinv[n] = rsqrtf((float)(deg[n] + 1));  // self-loop adds 1
    }
}

// ---------------- 3-pass device-wide exclusive scan: deg -> rowptr[N+1] ----------
__global__ __launch_bounds__(1024) void blocksum_kernel(const int* __restrict__ deg,
                                                        int* __restrict__ bsum) {
    int i = blockIdx.x * 1024 + threadIdx.x;
    int v = (i < N_NODES) ? deg[i] : 0;
    __shared__ int s[1024];
    int t = threadIdx.x;
    s[t] = v;
    __syncthreads();
#pragma unroll
    for (int off = 512; off > 0; off >>= 1) {
        if (t < off) s[t] += s[t + off];
        __syncthreads();
    }
    if (t == 0) bsum[blockIdx.x] = s[0];
}

__global__ __launch_bounds__(128) void bscan_kernel(int* __restrict__ bsum) {
    __shared__ int s[128];
    int t = threadIdx.x;
    int v = (t < SCAN_BLOCKS) ? bsum[t] : 0;
    s[t] = v;
    __syncthreads();
#pragma unroll
    for (int off = 1; off < 128; off <<= 1) {
        int x = (t >= off) ? s[t - off] : 0;
        __syncthreads();
        s[t] += x;
        __syncthreads();
    }
    if (t < SCAN_BLOCKS) bsum[t] = (t > 0) ? s[t - 1] : 0;  // exclusive
}

__global__ __launch_bounds__(1024) void scanout_kernel(const int* __restrict__ deg,
                                                       const int* __restrict__ bsum,
                                                       int* __restrict__ rowptr) {
    int i = blockIdx.x * 1024 + threadIdx.x;
    int t = threadIdx.x;
    int v = (i < N_NODES) ? deg[i] : 0;
    __shared__ int s[1024];
    s[t] = v;
    __syncthreads();
#pragma unroll
    for (int off = 1; off < 1024; off <<= 1) {
        int x = (t >= off) ? s[t - off] : 0;
        __syncthreads();
        s[t] += x;
        __syncthreads();
    }
    int base = bsum[blockIdx.x];
    int excl = (t > 0) ? s[t - 1] : 0;
    if (i < N_NODES) rowptr[i] = base + excl;
    if (i == N_NODES - 1) rowptr[N_NODES] = base + s[t];
}

// ---------------- bucket fill: CSR src list sorted by dst ----------------
__global__ void fill_kernel(const int* __restrict__ ei, const int* __restrict__ rowptr,
                            int* __restrict__ fill, int* __restrict__ esrc) {
    int e = blockIdx.x * blockDim.x + threadIdx.x;
    if (e < N_EDGES) {
        int dst = ei[N_EDGES + e];
        int pos = rowptr[dst] + atomicAdd(&fill[dst], 1);
        esrc[pos] = ei[e];
    }
}

// ---------------- x -> bf16 ----------------
__global__ void x2bf_kernel(const float* __restrict__ x, unsigned short* __restrict__ xb) {
    size_t i = ((size_t)blockIdx.x * 256 + threadIdx.x) * 4;
    float4 v = *(const float4*)(x + i);
    ushort4 o;
    o.x = f2bf(v.x); o.y = f2bf(v.y); o.z = f2bf(v.z); o.w = f2bf(v.w);
    *(ushort4*)(xb + i) = o;
}

// ---------------- weight transpose + bf16 split: W[K][256] -> Wt_hi/lo[256][K] -----
template <int K>
__global__ void wsplit_kernel(const float* __restrict__ W, unsigned short* __restrict__ Wth,
                              unsigned short* __restrict__ Wtl) {
    int idx = blockIdx.x * 256 + threadIdx.x;
    if (idx >= K * 256) return;
    int k = idx >> 8, n = idx & 255;
    float w = W[idx];
    unsigned short h = f2bf(w);
    unsigned short l = f2bf(w - bf2f(h));
    Wth[n * K + k] = h;
    Wtl[n * K + k] = l;
}

// ---------------- gather agg 128-dim from bf16, writes bf16 hi/lo split ----------
__global__ __launch_bounds__(256) void agg128_kernel(const unsigned short* __restrict__ X,
                                                     const int* __restrict__ esrc,
                                                     const int* __restrict__ rowptr,
                                                     const float* __restrict__ dinv,
                                                     unsigned short* __restrict__ Ah,
                                                     unsigned short* __restrict__ Al) {
    int node = blockIdx.x * 4 + (threadIdx.x >> 6);
    int lane = threadIdx.x & 63;
    if (node >= N_NODES) return;
    float ddst = dinv[node];
    int s = rowptr[node], e = rowptr[node + 1];

    float w0 = ddst * ddst;
    ushort2 h0 = *(const ushort2*)(X + (size_t)node * 128 + lane * 2);
    float2 acc = make_float2(w0 * bf2f(h0.x), w0 * bf2f(h0.y));

    int j = s;
    for (; j + 8 <= e; j += 8) {
        int si[8];
#pragma unroll
        for (int u = 0; u < 8; u++) si[u] = esrc[j + u];
        ushort2 xv[8];
#pragma unroll
        for (int u = 0; u < 8; u++)
            xv[u] = *(const ushort2*)(X + (size_t)si[u] * 128 + lane * 2);
        float a[8];
#pragma unroll
        for (int u = 0; u < 8; u++) a[u] = dinv[si[u]] * ddst;
#pragma unroll
        for (int u = 0; u < 8; u++) {
            acc.x = fmaf(a[u], bf2f(xv[u].x), acc.x);
            acc.y = fmaf(a[u], bf2f(xv[u].y), acc.y);
        }
    }
    for (; j < e; j++) {
        int src = esrc[j];
        float w = dinv[src] * ddst;
        ushort2 xv = *(const ushort2*)(X + (size_t)src * 128 + lane * 2);
        acc.x = fmaf(w, bf2f(xv.x), acc.x);
        acc.y = fmaf(w, bf2f(xv.y), acc.y);
    }
    size_t o = (size_t)node * 128 + lane * 2;
    ushort2 hi, lo;
    hi.x = f2bf(acc.x); lo.x = f2bf(acc.x - bf2f(hi.x));
    hi.y = f2bf(acc.y); lo.y = f2bf(acc.y - bf2f(hi.y));
    *(ushort2*)(Ah + o) = hi;
    *(ushort2*)(Al + o) = lo;
}

// ---------------- gather agg 256-dim from bf16, writes bf16 hi/lo split ----------
__global__ __launch_bounds__(256) void agg256_kernel(const unsigned short* __restrict__ H,
                                                     const int* __restrict__ esrc,
                                                     const int* __restrict__ rowptr,
                                                     const float* __restrict__ dinv,
                                                     unsigned short* __restrict__ Ah,
                                                     unsigned short* __restrict__ Al) {
    int node = blockIdx.x * 4 + (threadIdx.x >> 6);
    int lane = threadIdx.x & 63;
    if (node >= N_NODES) return;
    float ddst = dinv[node];
    int s = rowptr[node], e = rowptr[node + 1];

    float w0 = ddst * ddst;
    ushort4 h0 = *(const ushort4*)(H + (size_t)node * 256 + lane * 4);
    float4 acc = make_float4(w0 * bf2f(h0.x), w0 * bf2f(h0.y),
                             w0 * bf2f(h0.z), w0 * bf2f(h0.w));

    int j = s;
    for (; j + 8 <= e; j += 8) {
        int si[8];
#pragma unroll
        for (int u = 0; u < 8; u++) si[u] = esrc[j + u];
        ushort4 xv[8];
#pragma unroll
        for (int u = 0; u < 8; u++)
            xv[u] = *(const ushort4*)(H + (size_t)si[u] * 256 + lane * 4);
        float a[8];
#pragma unroll
        for (int u = 0; u < 8; u++) a[u] = dinv[si[u]] * ddst;
#pragma unroll
        for (int u = 0; u < 8; u++) {
            acc.x = fmaf(a[u], bf2f(xv[u].x), acc.x);
            acc.y = fmaf(a[u], bf2f(xv[u].y), acc.y);
            acc.z = fmaf(a[u], bf2f(xv[u].z), acc.z);
            acc.w = fmaf(a[u], bf2f(xv[u].w), acc.w);
        }
    }
    for (; j < e; j++) {
        int src = esrc[j];
        float w = dinv[src] * ddst;
        ushort4 xv = *(const ushort4*)(H + (size_t)src * 256 + lane * 4);
        acc.x = fmaf(w, bf2f(xv.x), acc.x);
        acc.y = fmaf(w, bf2f(xv.y), acc.y);
        acc.z = fmaf(w, bf2f(xv.z), acc.z);
        acc.w = fmaf(w, bf2f(xv.w), acc.w);
    }
    size_t o = (size_t)node * 256 + lane * 4;
    ushort4 hi, lo;
    hi.x = f2bf(acc.x); lo.x = f2bf(acc.x - bf2f(hi.x));
    hi.y = f2bf(acc.y); lo.y = f2bf(acc.y - bf2f(hi.y));
    hi.z = f2bf(acc.z); lo.z = f2bf(acc.z - bf2f(hi.z));
    hi.w = f2bf(acc.w); lo.w = f2bf(acc.w - bf2f(hi.w));
    *(ushort4*)(Ah + o) = hi;
    *(ushort4*)(Al + o) = lo;
}

// ---------------- MFMA bf16x3 GEMM: C = relu(A @ W + b) ----------
template <int K, bool BF16OUT>
__launch_bounds__(256, 2)
__global__ void mfma_gemm_bias_relu(const unsigned short* __restrict__ Ah,
                                    const unsigned short* __restrict__ Al,
                                    const unsigned short* __restrict__ Bh,
                                    const unsigned short* __restrict__ Bl,
                                    const float* __restrict__ bias,
                                    void* __restrict__ Cout) {
    __shared__ __align__(16) unsigned short lds[4 * 128 * 32];
    unsigned short* Ahs = lds;
    unsigned short* Als = lds + 4096;
    unsigned short* Bhs = lds + 8192;
    unsigned short* Bls = lds + 12288;

    int tid = threadIdx.x;
    int bm = blockIdx.x * 128;
    int bn = blockIdx.y * 128;
    int wid = tid >> 6, lane = tid & 63;
    int wm = wid & 1, wn = wid >> 1;
    int lrow = lane & 15, quad = lane >> 4;

    f32x4 acc[4][4];
#pragma unroll
    for (int mi = 0; mi < 4; mi++)
#pragma unroll
        for (int ni = 0; ni < 4; ni++) acc[mi][ni] = (f32x4){0.f, 0.f, 0.f, 0.f};

    for (int k0 = 0; k0 < K; k0 += 32) {
#pragma unroll
        for (int i = 0; i < 8; i++) {
            int c = tid + 256 * i;
            int tile = c >> 9;
            int w = c & 511;
            int row = w >> 2;
            int part = w & 3;
            const unsigned short* g;
            if (tile == 0)      g = Ah + (size_t)(bm + row) * K + k0 + part * 8;
            else if (tile == 1) g = Al + (size_t)(bm + row) * K + k0 + part * 8;
            else if (tile == 2) g = Bh + (size_t)(bn + row) * K + k0 + part * 8;
            else                g = Bl + (size_t)(bn + row) * K + k0 + part * 8;
            ulonglong2 v = *(const ulonglong2*)g;
            *(ulonglong2*)&lds[(tile << 12) + row * 32 + part * 8] = v;
        }
        __syncthreads();

        bf16x8 ah[4], al[4], bh[4], bl[4];
#pragma unroll
        for (int mi = 0; mi < 4; mi++) {
            int r = wm * 64 + mi * 16 + lrow;
            ah[mi] = *(const bf16x8*)&Ahs[r * 32 + quad * 8];
            al[mi] = *(const bf16x8*)&Als[r * 32 + quad * 8];
        }
#pragma unroll
        for (int ni = 0; ni < 4; ni++) {
            int r = wn * 64 + ni * 16 + lrow;
            bh[ni] = *(const bf16x8*)&Bhs[r * 32 + quad * 8];
            bl[ni] = *(const bf16x8*)&Bls[r * 32 + quad * 8];
        }
#pragma unroll
        for (int mi = 0; mi < 4; mi++)
#pragma unroll
            for (int ni = 0; ni < 4; ni++) {
                acc[mi][ni] = __builtin_amdgcn_mfma_f32_16x16x32_bf16(ah[mi], bh[ni], acc[mi][ni], 0, 0, 0);
                acc[mi][ni] = __builtin_amdgcn_mfma_f32_16x16x32_bf16(ah[mi], bl[ni], acc[mi][ni], 0, 0, 0);
                acc[mi][ni] = __builtin_amdgcn_mfma_f32_16x16x32_bf16(al[mi], bh[ni], acc[mi][ni], 0, 0, 0);
            }
        __syncthreads();
    }

    float bv[4];
#pragma unroll
    for (int ni = 0; ni < 4; ni++) bv[ni] = bias[bn + wn * 64 + ni * 16 + lrow];
#pragma unroll
    for (int mi = 0; mi < 4; mi++) {
        int row0 = bm + wm * 64 + mi * 16 + quad * 4;
#pragma unroll
        for (int ni = 0; ni < 4; ni++) {
            int col = bn + wn * 64 + ni * 16 + lrow;
#pragma unroll
            for (int r = 0; r < 4; r++) {
                int row = row0 + r;
                if (row < N_NODES) {
                    float v = fmaxf(acc[mi][ni][r] + bv[ni], 0.f);
                    if (BF16OUT)
                        ((unsigned short*)Cout)[(size_t)row * 256 + col] = f2bf(v);
                    else
                        ((float*)Cout)[(size_t)row * 256 + col] = v;
                }
            }
        }
    }
}

// ---------------- fused mean-pool (batch sorted) + MLP head ----------------
__global__ __launch_bounds__(256) void pool_mlp_kernel(const float* __restrict__ h,
                                                       const int* __restrict__ batch,
                                                       const float* __restrict__ Wf1,
                                                       const float* __restrict__ bf1,
                                                       const float* __restrict__ Wf2,
                                                       const float* __restrict__ bf2,
                                                       float* __restrict__ out) {
    int g = blockIdx.x;
    int t = threadIdx.x;  // 0..255
    __shared__ int bounds[2];
    if (t < 2) {
        int target = g + t;
        int lo = 0, hi = N_NODES;
        while (lo < hi) {
            int mid = (lo + hi) >> 1;
            if (batch[mid] < target) lo = mid + 1;
            else hi = mid;
        }
        bounds[t] = lo;
    }
    __syncthreads();
    int lo = bounds[0], hi = bounds[1];

    float acc = 0.f;
    for (int n = lo; n < hi; n++) acc += h[(size_t)n * HID + t];
    float inv = (hi > lo) ? 1.0f / (float)(hi - lo) : 0.f;
    __shared__ float p[256];
    p[t] = acc * inv;
    __syncthreads();

    float hv = 0.f;
    if (t < 128) {
        float a = bf1[t];
#pragma unroll 8
        for (int k = 0; k < 256; k++) a = fmaf(p[k], Wf1[k * 128 + t], a);
        hv = fmaxf(a, 0.f) * Wf2[t];
    }
#pragma unroll
    for (int off = 32; off > 0; off >>= 1) hv += __shfl_down(hv, off, 64);
    __shared__ float partial[4];
    if ((t & 63) == 0) partial[t >> 6] = hv;
    __syncthreads();
    if (t == 0) out[g] = partial[0] + partial[1] + bf2[0];
}

extern "C" void kernel_launch(void* const* d_in, const int* in_sizes, int n_in,
                              void* d_out, int out_size, void* d_ws, size_t ws_size,
                              hipStream_t stream) {
    const float* x   = (const float*)d_in[0];
    const int*   ei  = (const int*)d_in[1];
    const int*   bat = (const int*)d_in[2];
    const float* W1  = (const float*)d_in[3];
    const float* b1  = (const float*)d_in[4];
    const float* W2  = (const float*)d_in[5];
    const float* b2  = (const float*)d_in[6];
    const float* Wf1 = (const float*)d_in[7];
    const float* bf1 = (const float*)d_in[8];
    const float* Wf2 = (const float*)d_in[9];
    const float* bf2 = (const float*)d_in[10];
    float* out = (float*)d_out;

    char* ws = (char*)d_ws;
    // layout (time-multiplexed; peak end 0xCBE8000 = 213.9 MB):
    //   0x0000000 deg        0x0080000 dinv      0x0100000 rowptr   0x0180000 fill
    //   0x01F0000 bsum (98 int)
    //   0x0200000 esrc (6.4 MB)
    //   0x0820000 W1th  0x0830000 W1tl  0x0840000 W2th  0x0860000 W2tl
    //   A1h @ 0x0880000, A1l @ 0x20F0000 ; A2h @ 0x0880000, A2l @ 0x3960000
    //   xbf/H1bf/bufC @ 0x6A40000 (time-multiplexed)
    int*   deg    = (int*)(ws);
    float* dinv   = (float*)(ws + 0x0080000);
    int*   rowptr = (int*)(ws + 0x0100000);
    int*   fill   = (int*)(ws + 0x0180000);
    int*   bsum   = (int*)(ws + 0x01F0000);
    int*   esrc   = (int*)(ws + 0x0200000);
    unsigned short* W1th = (unsigned short*)(ws + 0x0820000);
    unsigned short* W1tl = (unsigned short*)(ws + 0x0830000);
    unsigned short* W2th = (unsigned short*)(ws + 0x0840000);
    unsigned short* W2tl = (unsigned short*)(ws + 0x0860000);
    unsigned short* A1h  = (unsigned short*)(ws + 0x0880000);
    unsigned short* A1l  = (unsigned short*)(ws + 0x20F0000);
    unsigned short* A2h  = (unsigned short*)(ws + 0x0880000);
    unsigned short* A2l  = (unsigned short*)(ws + 0x3960000);
    unsigned short* xbf  = (unsigned short*)(ws + 0x6A40000);
    unsigned short* H1bf = (unsigned short*)(ws + 0x6A40000);
    float* bufC = (float*)(ws + 0x6A40000);

    hipMemsetAsync(deg, 0, (size_t)N_NODES * sizeof(int), stream);
    hipMemsetAsync(fill, 0, (size_t)N_NODES * sizeof(int), stream);

    // independent prep
    x2bf_kernel<<<(N_NODES * IN_DIM / 4) / 256, 256, 0, stream>>>(x, xbf);
    wsplit_kernel<IN_DIM><<<(IN_DIM * 256) / 256, 256, 0, stream>>>(W1, W1th, W1tl);
    wsplit_kernel<HID><<<(HID * 256) / 256, 256, 0, stream>>>(W2, W2th, W2tl);

    // CSR build
    count_deg_kernel<<<(N_EDGES + 255) / 256, 256, 0, stream>>>(ei, deg);
    dinv_kernel<<<(N_NODES + 255) / 256, 256, 0, stream>>>(deg, dinv);
    blocksum_kernel<<<SCAN_BLOCKS, 1024, 0, stream>>>(deg, bsum);
    bscan_kernel<<<1, 128, 0, stream>>>(bsum);
    scanout_kernel<<<SCAN_BLOCKS, 1024, 0, stream>>>(deg, bsum, rowptr);
    fill_kernel<<<(N_EDGES + 255) / 256, 256, 0, stream>>>(ei, rowptr, fill, esrc);

    // layer 1: A1 = split(A~ x_bf16); H1bf = bf16(relu(A1 @ W1 + b1))
    agg128_kernel<<<N_NODES / 4, 256, 0, stream>>>(xbf, esrc, rowptr, dinv, A1h, A1l);
    {
        dim3 grid(M_PAD / 128, 2);
        mfma_gemm_bias_relu<IN_DIM, true><<<grid, 256, 0, stream>>>(A1h, A1l, W1th, W1tl, b1, H1bf);
    }

    // layer 2: A2 = split(A~ H1bf); C2 = relu(A2 @ W2 + b2) f32
    agg256_kernel<<<N_NODES / 4, 256, 0, stream>>>(H1bf, esrc, rowptr, dinv, A2h, A2l);
    {
        dim3 grid(M_PAD / 128, 2);
        mfma_gemm_bias_relu<HID, false><<<grid, 256, 0, stream>>>(A2h, A2l, W2th, W2tl, b2, bufC);
    }

    // pooling + MLP head
    pool_mlp_kernel<<<NUM_GRAPHS, 256, 0, stream>>>(bufC, bat, Wf1, bf1, Wf2, bf2, out);
}